// Round 15
// baseline (4117.262 us; speedup 1.0000x reference)
//
#include <hip/hip_runtime.h>
#include <math.h>

#define B_TOT 4096
#define N_SEQ 28
#define NDIM 3
#define ED 512
#define DD 256
#define NH 8
#define DHD 64
#define EMLP 2048
#define DMLP 1024
#define NM 14
#define NU 14

typedef __attribute__((ext_vector_type(8))) short short8;
typedef __attribute__((ext_vector_type(4))) float f32x4;
typedef unsigned short ushort_t;
typedef unsigned int uint_t;

// ---------------- helpers ----------------
__device__ __forceinline__ float gelu_f(float x) {
    float t = 0.7978845608028654f * (x + 0.044715f * x * x * x);
    float e = __expf(2.0f * t);
    float th = 1.0f - 2.0f / (e + 1.0f);   // tanh(t), overflow-safe
    return 0.5f * x * (1.0f + th);
}
__device__ __forceinline__ ushort_t f2bf(float f) {
    union { float f; uint_t u; } c; c.f = f;
    uint_t u = c.u;
    return (ushort_t)((u + 0x7FFFu + ((u >> 16) & 1u)) >> 16);
}
__device__ __forceinline__ float bf2f(ushort_t h) {
    union { uint_t u; float f; } c; c.u = ((uint_t)h) << 16;
    return c.f;
}
__device__ __forceinline__ float bf_lo(uint_t u) {
    union { uint_t u; float f; } c; c.u = u << 16;
    return c.f;
}
__device__ __forceinline__ float bf_hi(uint_t u) {
    union { uint_t u; float f; } c; c.u = u & 0xFFFF0000u;
    return c.f;
}
// packed f32x2 -> bf16x2 (RNE), single VALU op
__device__ __forceinline__ uint_t cvtpk(float lo, float hi) {
    uint_t r;
    asm volatile("v_cvt_pk_bf16_f32 %0, %1, %2" : "=v"(r) : "v"(lo), "v"(hi));
    return r;
}
__device__ __forceinline__ void gl_lds16(const ushort_t* g, ushort_t* l) {
    __builtin_amdgcn_global_load_lds(
        (const __attribute__((address_space(1))) unsigned int*)g,
        (__attribute__((address_space(3))) unsigned int*)l, 16, 0, 0);
}

// ---------------- zero / finalize ----------------
__global__ void k_zero(float* p) { p[threadIdx.x] = 0.0f; }
__global__ void k_final(const float* acc, float* out) {
    out[0] = acc[0] * (1.0f / (float)(B_TOT * NM * NDIM));
}

// ---------------- weight transpose + bf16 convert: Wt[n][k] = bf(W[k][n]) ----------------
__global__ void k_wconv(const float* __restrict__ W, ushort_t* __restrict__ Wt, int K, int N) {
    __shared__ float tile[32][33];
    int n0 = blockIdx.x * 32, k0 = blockIdx.y * 32;
    int tr = threadIdx.x >> 5, tc = threadIdx.x & 31;  // 8 x 32
#pragma unroll
    for (int i = 0; i < 4; ++i)
        tile[tr + i * 8][tc] = W[(size_t)(k0 + tr + i * 8) * N + n0 + tc];
    __syncthreads();
#pragma unroll
    for (int i = 0; i < 4; ++i)
        Wt[(size_t)(n0 + tr + i * 8) * K + k0 + tc] = f2bf(tile[tc][tr + i * 8]);
}

// ---------------- embed + gathers (bf16 X out) ----------------
__global__ void k_embed(const float* __restrict__ x, const float* __restrict__ a,
                        const int* __restrict__ mi, const int* __restrict__ ui,
                        const float* __restrict__ W_emb, const float* __restrict__ b_emb,
                        const float* __restrict__ pos_emb,
                        ushort_t* __restrict__ X, float* __restrict__ ua,
                        float* __restrict__ out_mn, float* __restrict__ out_midx,
                        int base) {
    int s = blockIdx.x;
    int g = base + s;
    int t = threadIdx.x;
    for (int i = 0; i < NU; ++i) {
        int u = ui[g * NU + i];
        float x0 = x[((size_t)g * N_SEQ + u) * NDIM + 0];
        float x1 = x[((size_t)g * N_SEQ + u) * NDIM + 1];
        float x2 = x[((size_t)g * N_SEQ + u) * NDIM + 2];
        for (int d = t; d < ED; d += 256) {
            X[((size_t)s * NU + i) * ED + d] = f2bf(
                x0 * W_emb[d] + x1 * W_emb[ED + d] + x2 * W_emb[2 * ED + d]
                + b_emb[d] + pos_emb[(size_t)u * ED + d]);
        }
    }
    for (int idx = t; idx < NU * NU; idx += 256) {
        int i = idx / NU, j = idx % NU;
        int uii = ui[g * NU + i], ujj = ui[g * NU + j];
        ua[(size_t)s * NU * NU + idx] = a[(size_t)g * N_SEQ * N_SEQ + (size_t)uii * N_SEQ + ujj];
    }
    for (int idx = t; idx < NM * NDIM; idx += 256) {
        int i = idx / NDIM, c = idx % NDIM;
        int m = mi[g * NM + i];
        out_mn[((size_t)g * NM + i) * NDIM + c] = x[((size_t)g * N_SEQ + m) * NDIM + c];
    }
    for (int i = t; i < NM; i += 256) {
        out_midx[(size_t)g * NM + i] = (float)mi[g * NM + i];
    }
}

// ---------------- layernorm: bf16 in -> bf16 out ----------------
template <int D>
__global__ void k_ln(const ushort_t* __restrict__ in, ushort_t* __restrict__ out,
                     const float* __restrict__ sc, const float* __restrict__ bi, int M) {
    int wave = threadIdx.x >> 6;
    int lane = threadIdx.x & 63;
    int row = blockIdx.x * 4 + wave;
    if (row >= M) return;
    constexpr int PL = D / 64;  // 8 (ED) or 4 (DD)
    const ushort_t* rp = in + (size_t)row * D + lane * PL;
    uint_t u[PL / 2];
    if (PL == 8) *(uint4*)u = *(const uint4*)rp;
    else *(uint2*)u = *(const uint2*)rp;
    float v[PL];
    float sum = 0.f, sq = 0.f;
#pragma unroll
    for (int q = 0; q < PL / 2; ++q) {
        v[2 * q] = bf_lo(u[q]);
        v[2 * q + 1] = bf_hi(u[q]);
    }
#pragma unroll
    for (int j = 0; j < PL; ++j) { sum += v[j]; sq += v[j] * v[j]; }
#pragma unroll
    for (int o = 32; o >= 1; o >>= 1) {
        sum += __shfl_xor(sum, o);
        sq += __shfl_xor(sq, o);
    }
    float mean = sum * (1.0f / D);
    float var = sq * (1.0f / D) - mean * mean;
    float r = rsqrtf(var + 1e-5f);
    uint_t w[PL / 2];
#pragma unroll
    for (int q = 0; q < PL / 2; ++q) {
        int d = lane * PL + 2 * q;
        float a0 = (v[2 * q] - mean) * r * sc[d] + bi[d];
        float a1 = (v[2 * q + 1] - mean) * r * sc[d + 1] + bi[d + 1];
        w[q] = (uint_t)f2bf(a0) | ((uint_t)f2bf(a1) << 16);
    }
    ushort_t* op = out + (size_t)row * D + lane * PL;
    if (PL == 8) *(uint4*)op = *(uint4*)w;
    else *(uint2*)op = *(uint2*)w;
}

// ---------------- bf16 MFMA GEMM: 256x256 tile, 8 waves (4Mx2N), 2-stage dbuf ----------------
// A: MxK bf16 row-major, row stride lda. Wt: NxK bf16 (stride K). C = act(A@Wt^T+bias+res).
// grid = (N/256, M/256), XCD-swizzled. 512 thr = 8 waves; wave w: wr=w>>1 (rows wr*64..+64),
// wc=w&1 (cols wc*128..+128); acc[4][8] = 32 MFMA per K-32 step fed by 12 ds_read_b128.
// 2-stage double buffer (proven r5 pattern): stage(t+1) -> vmcnt(4) -> barrier ->
// compute(t) -> barrier. 4 gl_lds per thread per stage -> vmcnt(4) (T4 formula).
// Chunk swizzle (rule #21 both-sides): source scol ^= (lane>>3)&3, read kq ^= (l15>>1)&3.
// M%256==0, N%256==0, K%32==0.
template <int ACT>
__global__ __launch_bounds__(512, 2) void k_gemm_mfma(
    const ushort_t* __restrict__ A, const ushort_t* __restrict__ Wt,
    const float* __restrict__ bias, const ushort_t* __restrict__ res,
    ushort_t* __restrict__ Cout, int M, int N, int K, int lda) {
    // 2 stages x (A 256x32 + B 256x32) u16 = 2 x 16384 u16 = 64KB; epilogue Cs[128][136] reuses
    __shared__ __align__(16) ushort_t smem[32768];

    const int t = threadIdx.x;
    // bijective XCD swizzle (m204)
    const int gx = gridDim.x;
    int flat = blockIdx.y * gx + blockIdx.x;
    int nwg = gx * gridDim.y;
    int q8 = nwg >> 3, r8 = nwg & 7;
    int xcd = flat & 7, loc = flat >> 3;
    int wg = (xcd < r8 ? xcd * (q8 + 1) : r8 * (q8 + 1) + (xcd - r8) * q8) + loc;
    const int bm = wg / gx, bn = wg % gx;

    const int lane = t & 63;
    const int wave = t >> 6;             // 0..7
    const int wr = wave >> 1, wc = wave & 1;
    const int l15 = lane & 15;
    const int g4 = lane >> 4;
    const int kq = (g4 ^ ((l15 >> 1) & 3)) * 8;   // swizzled read chunk

    const int srow = wave * 32 + (lane >> 2);     // staging row 0..255
    const int scol = ((lane & 3) ^ ((lane >> 3) & 3)) * 8;  // pre-swizzled source chunk
    const ushort_t* Ag = A + (size_t)(bm * 256 + srow) * lda + scol;
    const ushort_t* Bg = Wt + (size_t)(bn * 256 + srow) * K + scol;
    const int wb0 = wave * 1024;         // wave staging base (u16): (wave*32)*32

    // per-lane fragment read bases (u16): buffer offset cur*16384 added at use
    const ushort_t* Ard = smem + (wr * 64 + l15) * 32 + kq;
    const ushort_t* Brd = smem + 8192 + (wc * 128 + l15) * 32 + kq;

    f32x4 acc[4][8] = {};
    const int nt = K >> 5;

#define STAGE(tile, b)                                            \
    do {                                                          \
        int k0_ = (tile) << 5;                                    \
        ushort_t* Ab_ = smem + (b) * 16384;                       \
        gl_lds16(Ag + k0_, Ab_ + wb0);                            \
        gl_lds16(Ag + (size_t)16 * lda + k0_, Ab_ + wb0 + 512);   \
        gl_lds16(Bg + k0_, Ab_ + 8192 + wb0);                     \
        gl_lds16(Bg + (size_t)16 * K + k0_, Ab_ + 8192 + wb0 + 512); \
    } while (0)

    // prologue: stage tile 0 -> buf0
    STAGE(0, 0);

    for (int tt = 0; tt < nt; ++tt) {
        if (tt + 1 < nt) {
            STAGE(tt + 1, (tt + 1) & 1);
            asm volatile("s_waitcnt vmcnt(4)" ::: "memory");
        } else {
            asm volatile("s_waitcnt vmcnt(0)" ::: "memory");
        }
        __builtin_amdgcn_s_barrier();
        __builtin_amdgcn_sched_barrier(0);
        const int bo = (tt & 1) * 16384;
        short8 af[4], bfr[8];
#pragma unroll
        for (int m = 0; m < 4; ++m)
            af[m] = *(const short8*)(Ard + bo + m * 512);
#pragma unroll
        for (int n = 0; n < 8; ++n)
            bfr[n] = *(const short8*)(Brd + bo + n * 512);
        __builtin_amdgcn_s_setprio(1);
#pragma unroll
        for (int m = 0; m < 4; ++m)
#pragma unroll
            for (int n = 0; n < 8; ++n)
                acc[m][n] = __builtin_amdgcn_mfma_f32_16x16x32_bf16(af[m], bfr[n], acc[m][n], 0, 0, 0);
        __builtin_amdgcn_s_setprio(0);
        __builtin_amdgcn_sched_barrier(0);
        __builtin_amdgcn_s_barrier();
    }
#undef STAGE

    // ---- epilogue: 4 quadrant passes (hp = row half, cp = col half) through Cs[128][136] ----
    ushort_t* Cs = smem;
#pragma unroll
    for (int hp = 0; hp < 2; ++hp) {
#pragma unroll
        for (int cp = 0; cp < 2; ++cp) {
            if ((wave >> 2) == hp && (wave & 1) == cp) {
                const int erow0 = (wr & 1) * 64;
#pragma unroll
                for (int m = 0; m < 4; ++m)
#pragma unroll
                    for (int n = 0; n < 8; ++n)
#pragma unroll
                        for (int r = 0; r < 4; ++r) {
                            float v = acc[m][n][r];
                            float o = __shfl_xor(v, 1);
                            if (!(l15 & 1)) {
                                uint_t pk = cvtpk(v, o);
                                *(uint_t*)&Cs[(erow0 + m * 16 + g4 * 4 + r) * 136 + n * 16 + l15] = pk;
                            }
                        }
            }
            __builtin_amdgcn_s_barrier();
            const int row = t >> 2, q4 = t & 3;
            const int grow = bm * 256 + hp * 128 + row;
            const int gc0 = bn * 256 + cp * 128 + q4 * 32;
            const ushort_t* rres = res ? res + (size_t)grow * N + gc0 : (const ushort_t*)0;
            ushort_t* gout = Cout + (size_t)grow * N + gc0;
#pragma unroll
            for (int c = 0; c < 4; ++c) {
                uint4 pv = *(const uint4*)&Cs[row * 136 + q4 * 32 + c * 8];
                uint_t* pw = (uint_t*)&pv;
                float vv[8];
#pragma unroll
                for (int q = 0; q < 4; ++q) { vv[2 * q] = bf_lo(pw[q]); vv[2 * q + 1] = bf_hi(pw[q]); }
                if (bias) {
#pragma unroll
                    for (int j = 0; j < 8; ++j) vv[j] += bias[gc0 + c * 8 + j];
                }
                if (res) {
                    uint4 rv = *(const uint4*)(rres + c * 8);
                    uint_t* pr = (uint_t*)&rv;
#pragma unroll
                    for (int q = 0; q < 4; ++q) { vv[2 * q] += bf_lo(pr[q]); vv[2 * q + 1] += bf_hi(pr[q]); }
                }
                if (ACT == 1) {
#pragma unroll
                    for (int j = 0; j < 8; ++j) vv[j] = gelu_f(vv[j]);
                }
                uint4 ov;
                uint_t* po = (uint_t*)&ov;
#pragma unroll
                for (int q = 0; q < 4; ++q)
                    po[q] = cvtpk(vv[2 * q], vv[2 * q + 1]);
                *(uint4*)(gout + c * 8) = ov;
            }
            __builtin_amdgcn_s_barrier();
        }
    }
}

// ---------------- MFMA attention: block per (sequence, 4-head group) ----------------
// qkv bf16: rows (s*NT+n) stride 1536, cols [0,512)=q, [512,1024)=k, [1024,1536)=v.
// O is written IN-PLACE into the q-region. bias f32: [s][NT][NT].
template <int NT>
__global__ __launch_bounds__(256) void k_attn_mfma(
    ushort_t* __restrict__ qkv, const float* __restrict__ bias) {
    constexpr int NTP = (NT + 15) & ~15;  // 16 or 32
    constexpr int MT = NTP / 16;          // 1 or 2
    constexpr int QS = 72;                // q/k LDS row stride (u16)
    constexpr int VS = 40;                // vt/p LDS row stride (u16)
    __shared__ __align__(16) ushort_t smem[4 * NTP * QS * 2 + 4 * 64 * VS];
    ushort_t* Qs = smem;
    ushort_t* Ks = smem + 4 * NTP * QS;
    ushort_t* Vs = Ks + 4 * NTP * QS;
    ushort_t* Ps = smem;  // aliases Qs (dead after QK^T)

    const int s = blockIdx.x, hg = blockIdx.y;
    const int t = threadIdx.x;
    const int wave = t >> 6, lane = t & 63;
    const int l15 = lane & 15, g4 = lane >> 4;

    const ushort_t* qb = qkv + (size_t)s * NT * 1536 + hg * 256;
    for (int c = t; c < 64 * NT; c += 256) {
        int c8 = c & 7;
        int rem = c >> 3;
        int r = rem % NT;
        int ph = rem / NT;  // 0..7
        int h = ph & 3, p = ph >> 2;
        uint4 v = *(const uint4*)(qb + (size_t)r * 1536 + p * 512 + h * 64 + c8 * 8);
        ushort_t* dst = (p ? Ks : Qs) + (h * NTP + r) * QS + c8 * 8;
        *(uint4*)dst = v;
    }
    const ushort_t* vrow = qkv + (size_t)s * NT * 1536 + 1024 + hg * 256;
    for (int c = t; c < 4 * 64 * (32 - NT); c += 256) {
        int p = c % (32 - NT);
        int hd = c / (32 - NT);
        Vs[hd * VS + NT + p] = 0;
    }
    for (int c = t; c < 4 * NT * 8; c += 256) {
        int c8 = c & 7;
        int r = (c >> 3) % NT;
        int h = (c >> 3) / NT;
        uint4 v = *(const uint4*)(vrow + (size_t)r * 1536 + h * 64 + c8 * 8);
        const uint_t* pv = (const uint_t*)&v;
#pragma unroll
        for (int j = 0; j < 4; ++j) {
            Vs[(h * 64 + c8 * 8 + 2 * j) * VS + r] = (ushort_t)(pv[j] & 0xFFFFu);
            Vs[(h * 64 + c8 * 8 + 2 * j + 1) * VS + r] = (ushort_t)(pv[j] >> 16);
        }
    }
    __syncthreads();

    const int h = wave;
    const ushort_t* Qh = Qs + h * NTP * QS;
    const ushort_t* Kh = Ks + h * NTP * QS;
    const ushort_t* Vh = Vs + h * 64 * VS;
    ushort_t* Ph = Ps + h * NTP * VS;

    f32x4 sacc[MT][MT] = {};
#pragma unroll
    for (int ks = 0; ks < 2; ++ks) {
        short8 qf[MT], kf[MT];
#pragma unroll
        for (int m = 0; m < MT; ++m)
            qf[m] = *(const short8*)&Qh[(m * 16 + l15) * QS + ks * 32 + g4 * 8];
#pragma unroll
        for (int n = 0; n < MT; ++n)
            kf[n] = *(const short8*)&Kh[(n * 16 + l15) * QS + ks * 32 + g4 * 8];
#pragma unroll
        for (int m = 0; m < MT; ++m)
#pragma unroll
            for (int n = 0; n < MT; ++n)
                sacc[m][n] = __builtin_amdgcn_mfma_f32_16x16x32_bf16(qf[m], kf[n], sacc[m][n], 0, 0, 0);
    }

    const float* bp = bias + (size_t)s * NT * NT;
    float prv[MT][MT][4];
#pragma unroll
    for (int m = 0; m < MT; ++m) {
#pragma unroll
        for (int r = 0; r < 4; ++r) {
            int i = m * 16 + g4 * 4 + r;
            float sv[MT];
#pragma unroll
            for (int n = 0; n < MT; ++n) {
                int j = n * 16 + l15;
                sv[n] = (i < NT && j < NT) ? sacc[m][n][r] * 0.125f + bp[i * NT + j] : -1e30f;
            }
            float mx = sv[0];
            if (MT > 1) mx = fmaxf(mx, sv[MT - 1]);
#pragma unroll
            for (int o = 1; o < 16; o <<= 1) mx = fmaxf(mx, __shfl_xor(mx, o));
            float sum = 0.f;
#pragma unroll
            for (int n = 0; n < MT; ++n) {
                float e = (sv[n] > -1e29f) ? __expf(sv[n] - mx) : 0.f;
                prv[m][n][r] = e;
                sum += e;
            }
#pragma unroll
            for (int o = 1; o < 16; o <<= 1) sum += __shfl_xor(sum, o);
            float rs = sum > 0.f ? 1.0f / sum : 0.f;
#pragma unroll
            for (int n = 0; n < MT; ++n) prv[m][n][r] *= rs;
        }
    }
    __syncthreads();  // QK reads done before Ps (alias of Qs) written

    if (NTP == 16) {
        for (int z = lane; z < 16 * 8; z += 64) {
            int i = z >> 3, jw = z & 7;
            *(uint_t*)&Ph[i * VS + 16 + jw * 2] = 0;
        }
    }
#pragma unroll
    for (int m = 0; m < MT; ++m)
#pragma unroll
        for (int n = 0; n < MT; ++n)
#pragma unroll
            for (int r = 0; r < 4; ++r)
                Ph[(m * 16 + g4 * 4 + r) * VS + n * 16 + l15] = f2bf(prv[m][n][r]);
    __syncthreads();

    f32x4 oacc[MT][4] = {};
    {
        short8 pf[MT], vf[4];
#pragma unroll
        for (int m = 0; m < MT; ++m)
            pf[m] = *(const short8*)&Ph[(m * 16 + l15) * VS + g4 * 8];
#pragma unroll
        for (int nd = 0; nd < 4; ++nd)
            vf[nd] = *(const short8*)&Vh[(nd * 16 + l15) * VS + g4 * 8];
#pragma unroll
        for (int m = 0; m < MT; ++m)
#pragma unroll
            for (int nd = 0; nd < 4; ++nd)
                oacc[m][nd] = __builtin_amdgcn_mfma_f32_16x16x32_bf16(pf[m], vf[nd], oacc[m][nd], 0, 0, 0);
    }

    // ---- store O in-place into the q-region (row stride 1536) ----
    ushort_t* Ob = qkv + (size_t)s * NT * 1536 + hg * 256 + h * 64;
#pragma unroll
    for (int m = 0; m < MT; ++m)
#pragma unroll
        for (int r = 0; r < 4; ++r) {
            int i = m * 16 + g4 * 4 + r;
            if (i < NT) {
#pragma unroll
                for (int nd = 0; nd < 4; ++nd)
                    Ob[(size_t)i * 1536 + nd * 16 + l15] = f2bf(oacc[m][nd][r]);
            }
        }
}

// ---------------- decoder token assembly ----------------
__global__ void k_build_dec(const ushort_t* __restrict__ dec_tok, const float* __restrict__ mask_token,
                            const float* __restrict__ dec_pos, const int* __restrict__ mi,
                            ushort_t* __restrict__ Xd, float* __restrict__ out0, int base) {
    int s = blockIdx.x;
    int g = base + s;
    int t = threadIdx.x;
    for (int idx = t; idx < N_SEQ * DD; idx += 256) {
        int i = idx / DD, d = idx % DD;
        float v;
        if (i < NM) {
            int m = mi[g * NM + i];
            v = mask_token[d] + dec_pos[(size_t)m * DD + d];
        } else {
            v = bf2f(dec_tok[((size_t)s * NU + (i - NM)) * DD + d]);
        }
        Xd[((size_t)s * N_SEQ + i) * DD + d] = f2bf(v);
        out0[((size_t)g * N_SEQ + i) * DD + d] = v;
    }
}

// ---------------- prediction head + loss ----------------
__global__ void k_pred(const ushort_t* __restrict__ Xd, const int* __restrict__ mi,
                       const float* __restrict__ pW, const float* __restrict__ pb,
                       const float* __restrict__ mn, float* __restrict__ out_pred,
                       float* __restrict__ loss, int base, int Bc) {
    int tid = blockIdx.x * 256 + threadIdx.x;
    int total = Bc * NM * NDIM;
    float part = 0.f;
    if (tid < total) {
        int c = tid % NDIM;
        int r = tid / NDIM;
        int i = r % NM;
        int s = r / NM;
        int g = base + s;
        int m = mi[g * NM + i];
        const ushort_t* row = Xd + ((size_t)s * N_SEQ + m) * DD;
        float acc = pb[c];
        for (int k = 0; k < DD; ++k) acc += bf2f(row[k]) * pW[k * NDIM + c];
        out_pred[((size_t)g * NM + i) * NDIM + c] = acc;
        float d = acc - mn[((size_t)g * NM + i) * NDIM + c];
        part = d * d;
    }
    __shared__ float red[256];
    red[threadIdx.x] = part;
    __syncthreads();
    for (int o = 128; o > 0; o >>= 1) {
        if (threadIdx.x < o) red[threadIdx.x] += red[threadIdx.x + o];
        __syncthreads();
    }
    if (threadIdx.x == 0) atomicAdd(loss, red[0]);
}

// ---------------- host ----------------
extern "C" void kernel_launch(void* const* d_in, const int* in_sizes, int n_in,
                              void* d_out, int out_size, void* d_ws, size_t ws_size,
                              hipStream_t stream) {
    const float* x       = (const float*)d_in[0];
    const float* a       = (const float*)d_in[1];
    const int*   mi      = (const int*)d_in[2];
    const int*   ui      = (const int*)d_in[3];
    const float* W_emb   = (const float*)d_in[4];
    const float* b_emb   = (const float*)d_in[5];
    const float* pos_emb = (const float*)d_in[6];
    const float* e_ln1_s = (const float*)d_in[7];
    const float* e_ln1_b = (const float*)d_in[8];
    const float* e_Wqkv  = (const float*)d_in[9];
    const float* e_Wo    = (const float*)d_in[10];
    const float* e_bo    = (const float*)d_in[11];
    const float* e_ln2_s = (const float*)d_in[12];
    const float* e_ln2_b = (const float*)d_in[13];
    const float* e_W1    = (const float*)d_in[14];
    const float* e_b1    = (const float*)d_in[15];
    const float* e_W2    = (const float*)d_in[16];
    const float* e_b2    = (const float*)d_in[17];
    const float* e2d_W   = (const float*)d_in[18];
    const float* e2d_b   = (const float*)d_in[19];
    const float* mask_tok= (const float*)d_in[20];
    const float* dec_pos = (const float*)d_in[21];
    const float* d_ln1_s = (const float*)d_in[22];
    const float* d_ln1_b = (const float*)d_in[23];
    const float* d_Wqkv  = (const float*)d_in[24];
    const float* d_Wo    = (const float*)d_in[25];
    const float* d_bo    = (const float*)d_in[26];
    const float* d_ln2_s = (const float*)d_in[27];
    const float* d_ln2_b = (const float*)d_in[28];
    const float* d_W1    = (const float*)d_in[29];
    const float* d_b1    = (const float*)d_in[30];
    const float* d_W2    = (const float*)d_in[31];
    const float* d_b2    = (const float*)d_in[32];
    const float* pred_W  = (const float*)d_in[33];
    const float* pred_b  = (const float*)d_in[34];

    float* out0 = (float*)d_out;
    float* out1 = out0 + (size_t)B_TOT * N_SEQ * DD;
    float* out2 = out1 + (size_t)B_TOT * NM * NDIM;
    float* out3 = out2 + (size_t)B_TOT * NM;
    float* out4 = out3 + (size_t)B_TOT * NM * NDIM;

    // ---- workspace layout ----
    char* wp = (char*)d_ws;
    size_t off = 0;
    auto alloc = [&](size_t bytes) {
        size_t o = off;
        off = (off + bytes + 255) & ~(size_t)255;
        return (void*)(wp + o);
    };
    float* loss_acc = (float*)alloc(64 * 4);
    ushort_t* wt_eqkv = (ushort_t*)alloc((size_t)2 * 1536 * 512 * 2);
    ushort_t* wt_ewo  = (ushort_t*)alloc((size_t)2 * 512 * 512 * 2);
    ushort_t* wt_ew1  = (ushort_t*)alloc((size_t)2 * 2048 * 512 * 2);
    ushort_t* wt_ew2  = (ushort_t*)alloc((size_t)2 * 512 * 2048 * 2);
    ushort_t* wt_dqkv = (ushort_t*)alloc((size_t)1536 * 256 * 2);
    ushort_t* wt_dwo  = (ushort_t*)alloc((size_t)256 * 512 * 2);
    ushort_t* wt_dw1  = (ushort_t*)alloc((size_t)1024 * 256 * 2);
    ushort_t* wt_dw2  = (ushort_t*)alloc((size_t)256 * 1024 * 2);
    ushort_t* wt_e2d  = (ushort_t*)alloc((size_t)256 * 512 * 2);
    size_t fixed_bytes = off;

    // per-seq bytes: bf16 (X 7168 + H 7168 + QKV 43008) + f32 ua 196.
    // Dbuf aliases the head of QKVbuf (QKV dead when e2d writes; dqkv after build_dec).
    const size_t per_seq = 2 * (7168 + 7168 + 43008) + 4 * 196;
    int Bc = B_TOT;
    while (Bc > 128 && fixed_bytes + (size_t)Bc * per_seq + 8192 > ws_size) Bc >>= 1;

    ushort_t* Xbuf   = (ushort_t*)alloc((size_t)Bc * 7168 * 2);
    float*    uabuf  = (float*)alloc((size_t)Bc * 196 * 4);
    ushort_t* Hbuf   = (ushort_t*)alloc((size_t)Bc * 7168 * 2);
    ushort_t* QKVbuf = (ushort_t*)alloc((size_t)Bc * 43008 * 2);
    ushort_t* Dbuf   = QKVbuf;  // alias (see above)

    k_zero<<<1, 64, 0, stream>>>(loss_acc);

    // ---- weight conversion (once per launch) ----
    for (int l = 0; l < 2; ++l) {
        k_wconv<<<dim3(1536 / 32, 512 / 32), 256, 0, stream>>>(e_Wqkv + (size_t)l * 512 * 1536, wt_eqkv + (size_t)l * 1536 * 512, 512, 1536);
        k_wconv<<<dim3(512 / 32, 512 / 32), 256, 0, stream>>>(e_Wo + (size_t)l * 512 * 512, wt_ewo + (size_t)l * 512 * 512, 512, 512);
        k_wconv<<<dim3(2048 / 32, 512 / 32), 256, 0, stream>>>(e_W1 + (size_t)l * 512 * 2048, wt_ew1 + (size_t)l * 2048 * 512, 512, 2048);
        k_wconv<<<dim3(512 / 32, 2048 / 32), 256, 0, stream>>>(e_W2 + (size_t)l * 2048 * 512, wt_ew2 + (size_t)l * 512 * 2048, 2048, 512);
    }
    k_wconv<<<dim3(1536 / 32, 256 / 32), 256, 0, stream>>>(d_Wqkv, wt_dqkv, 256, 1536);
    k_wconv<<<dim3(256 / 32, 512 / 32), 256, 0, stream>>>(d_Wo, wt_dwo, 512, 256);
    k_wconv<<<dim3(1024 / 32, 256 / 32), 256, 0, stream>>>(d_W1, wt_dw1, 256, 1024);
    k_wconv<<<dim3(256 / 32, 1024 / 32), 256, 0, stream>>>(d_W2, wt_dw2, 1024, 256);
    k_wconv<<<dim3(256 / 32, 512 / 32), 256, 0, stream>>>(e2d_W, wt_e2d, 512, 256);

    const int nchunk = B_TOT / Bc;
    for (int c = 0; c < nchunk; ++c) {
        int base = c * Bc;
        int M = Bc * NU;
        int Md = Bc * N_SEQ;

        k_embed<<<Bc, 256, 0, stream>>>(x, a, mi, ui, W_emb, b_emb, pos_emb,
                                        Xbuf, uabuf, out1, out2, base);
        // ---- encoder ----
        for (int l = 0; l < 2; ++l) {
            k_ln<ED><<<M / 4, 256, 0, stream>>>(Xbuf, Hbuf, e_ln1_s + l * ED, e_ln1_b + l * ED, M);
            k_gemm_mfma<0><<<dim3(1536 / 256, M / 256), 512, 0, stream>>>(
                Hbuf, wt_eqkv + (size_t)l * 1536 * 512, nullptr, nullptr, QKVbuf, M, 1536, ED, ED);
            k_attn_mfma<NU><<<dim3(Bc, 2), 256, 0, stream>>>(QKVbuf, uabuf);
            k_gemm_mfma<0><<<dim3(ED / 256, M / 256), 512, 0, stream>>>(
                QKVbuf, wt_ewo + (size_t)l * 512 * 512, e_bo + l * ED, Xbuf, Xbuf, M, ED, 512, 1536);
            k_ln<ED><<<M / 4, 256, 0, stream>>>(Xbuf, Hbuf, e_ln2_s + l * ED, e_ln2_b + l * ED, M);
            k_gemm_mfma<1><<<dim3(EMLP / 256, M / 256), 512, 0, stream>>>(
                Hbuf, wt_ew1 + (size_t)l * 2048 * 512, e_b1 + l * EMLP, nullptr, QKVbuf, M, EMLP, ED, ED);
            k_gemm_mfma<0><<<dim3(ED / 256, M / 256), 512, 0, stream>>>(
                QKVbuf, wt_ew2 + (size_t)l * 512 * 2048, e_b2 + l * ED, Xbuf, Xbuf, M, ED, EMLP, EMLP);
        }
        // ---- encoder -> decoder ----
        k_gemm_mfma<0><<<dim3(DD / 256, M / 256), 512, 0, stream>>>(
            Xbuf, wt_e2d, e2d_b, nullptr, Dbuf, M, DD, ED, ED);
        k_build_dec<<<Bc, 256, 0, stream>>>(Dbuf, mask_tok, dec_pos, mi, Xbuf, out0, base);
        // ---- decoder ----
        k_ln<DD><<<Md / 4, 256, 0, stream>>>(Xbuf, Hbuf, d_ln1_s, d_ln1_b, Md);
        k_gemm_mfma<0><<<dim3(1536 / 256, Md / 256), 512, 0, stream>>>(
            Hbuf, wt_dqkv, nullptr, nullptr, QKVbuf, Md, 1536, DD, DD);
        k_attn_mfma<N_SEQ><<<dim3(Bc, 2), 256, 0, stream>>>(QKVbuf, a + (size_t)base * N_SEQ * N_SEQ);
        k_gemm_mfma<0><<<dim3(DD / 256, Md / 256), 512, 0, stream>>>(
            QKVbuf, wt_dwo, d_bo, Xbuf, Xbuf, Md, DD, 512, 1536);
        k_ln<DD><<<Md / 4, 256, 0, stream>>>(Xbuf, Hbuf, d_ln2_s, d_ln2_b, Md);
        k_gemm_mfma<1><<<dim3(DMLP / 256, Md / 256), 512, 0, stream>>>(
            Hbuf, wt_dw1, d_b1, nullptr, QKVbuf, Md, DMLP, DD, DD);
        k_gemm_mfma<0><<<dim3(DD / 256, Md / 256), 512, 0, stream>>>(
            QKVbuf, wt_dw2, d_b2, Xbuf, Xbuf, Md, DD, DMLP, DMLP);
        // ---- prediction + loss ----
        int tot = Bc * NM * NDIM;
        k_pred<<<(tot + 255) / 256, 256, 0, stream>>>(
            Xbuf, mi, pred_W, pred_b, out1, out3, loss_acc, base, Bc);
    }
    k_final<<<1, 1, 0, stream>>>(loss_acc, out4);
}

// Round 16
// 4105.786 us; speedup vs baseline: 1.0028x; 1.0028x over previous
//
#include <hip/hip_runtime.h>
#include <math.h>

#define B_TOT 4096
#define N_SEQ 28
#define NDIM 3
#define ED 512
#define DD 256
#define NH 8
#define DHD 64
#define EMLP 2048
#define DMLP 1024
#define NM 14
#define NU 14

typedef __attribute__((ext_vector_type(8))) short short8;
typedef __attribute__((ext_vector_type(4))) float f32x4;
typedef unsigned short ushort_t;
typedef unsigned int uint_t;

// ---------------- helpers ----------------
__device__ __forceinline__ float gelu_f(float x) {
    float t = 0.7978845608028654f * (x + 0.044715f * x * x * x);
    float e = __expf(2.0f * t);
    float th = 1.0f - 2.0f / (e + 1.0f);   // tanh(t), overflow-safe
    return 0.5f * x * (1.0f + th);
}
__device__ __forceinline__ ushort_t f2bf(float f) {
    union { float f; uint_t u; } c; c.f = f;
    uint_t u = c.u;
    return (ushort_t)((u + 0x7FFFu + ((u >> 16) & 1u)) >> 16);
}
__device__ __forceinline__ float bf2f(ushort_t h) {
    union { uint_t u; float f; } c; c.u = ((uint_t)h) << 16;
    return c.f;
}
__device__ __forceinline__ float bf_lo(uint_t u) {
    union { uint_t u; float f; } c; c.u = u << 16;
    return c.f;
}
__device__ __forceinline__ float bf_hi(uint_t u) {
    union { uint_t u; float f; } c; c.u = u & 0xFFFF0000u;
    return c.f;
}
// packed f32x2 -> bf16x2 (RNE), single VALU op
__device__ __forceinline__ uint_t cvtpk(float lo, float hi) {
    uint_t r;
    asm volatile("v_cvt_pk_bf16_f32 %0, %1, %2" : "=v"(r) : "v"(lo), "v"(hi));
    return r;
}
__device__ __forceinline__ void gl_lds16(const ushort_t* g, ushort_t* l) {
    __builtin_amdgcn_global_load_lds(
        (const __attribute__((address_space(1))) unsigned int*)g,
        (__attribute__((address_space(3))) unsigned int*)l, 16, 0, 0);
}

// ---------------- zero / finalize ----------------
__global__ void k_zero(float* p) { p[threadIdx.x] = 0.0f; }
__global__ void k_final(const float* acc, float* out) {
    out[0] = acc[0] * (1.0f / (float)(B_TOT * NM * NDIM));
}

// ---------------- weight transpose + bf16 convert: Wt[n][k] = bf(W[k][n]) ----------------
__global__ void k_wconv(const float* __restrict__ W, ushort_t* __restrict__ Wt, int K, int N) {
    __shared__ float tile[32][33];
    int n0 = blockIdx.x * 32, k0 = blockIdx.y * 32;
    int tr = threadIdx.x >> 5, tc = threadIdx.x & 31;  // 8 x 32
#pragma unroll
    for (int i = 0; i < 4; ++i)
        tile[tr + i * 8][tc] = W[(size_t)(k0 + tr + i * 8) * N + n0 + tc];
    __syncthreads();
#pragma unroll
    for (int i = 0; i < 4; ++i)
        Wt[(size_t)(n0 + tr + i * 8) * K + k0 + tc] = f2bf(tile[tc][tr + i * 8]);
}

// ---------------- embed + gathers (bf16 X out) ----------------
__global__ void k_embed(const float* __restrict__ x, const float* __restrict__ a,
                        const int* __restrict__ mi, const int* __restrict__ ui,
                        const float* __restrict__ W_emb, const float* __restrict__ b_emb,
                        const float* __restrict__ pos_emb,
                        ushort_t* __restrict__ X, float* __restrict__ ua,
                        float* __restrict__ out_mn, float* __restrict__ out_midx,
                        int base) {
    int s = blockIdx.x;
    int g = base + s;
    int t = threadIdx.x;
    for (int i = 0; i < NU; ++i) {
        int u = ui[g * NU + i];
        float x0 = x[((size_t)g * N_SEQ + u) * NDIM + 0];
        float x1 = x[((size_t)g * N_SEQ + u) * NDIM + 1];
        float x2 = x[((size_t)g * N_SEQ + u) * NDIM + 2];
        for (int d = t; d < ED; d += 256) {
            X[((size_t)s * NU + i) * ED + d] = f2bf(
                x0 * W_emb[d] + x1 * W_emb[ED + d] + x2 * W_emb[2 * ED + d]
                + b_emb[d] + pos_emb[(size_t)u * ED + d]);
        }
    }
    for (int idx = t; idx < NU * NU; idx += 256) {
        int i = idx / NU, j = idx % NU;
        int uii = ui[g * NU + i], ujj = ui[g * NU + j];
        ua[(size_t)s * NU * NU + idx] = a[(size_t)g * N_SEQ * N_SEQ + (size_t)uii * N_SEQ + ujj];
    }
    for (int idx = t; idx < NM * NDIM; idx += 256) {
        int i = idx / NDIM, c = idx % NDIM;
        int m = mi[g * NM + i];
        out_mn[((size_t)g * NM + i) * NDIM + c] = x[((size_t)g * N_SEQ + m) * NDIM + c];
    }
    for (int i = t; i < NM; i += 256) {
        out_midx[(size_t)g * NM + i] = (float)mi[g * NM + i];
    }
}

// ---------------- layernorm: bf16 in -> bf16 out ----------------
template <int D>
__global__ void k_ln(const ushort_t* __restrict__ in, ushort_t* __restrict__ out,
                     const float* __restrict__ sc, const float* __restrict__ bi, int M) {
    int wave = threadIdx.x >> 6;
    int lane = threadIdx.x & 63;
    int row = blockIdx.x * 4 + wave;
    if (row >= M) return;
    constexpr int PL = D / 64;  // 8 (ED) or 4 (DD)
    const ushort_t* rp = in + (size_t)row * D + lane * PL;
    uint_t u[PL / 2];
    if (PL == 8) *(uint4*)u = *(const uint4*)rp;
    else *(uint2*)u = *(const uint2*)rp;
    float v[PL];
    float sum = 0.f, sq = 0.f;
#pragma unroll
    for (int q = 0; q < PL / 2; ++q) {
        v[2 * q] = bf_lo(u[q]);
        v[2 * q + 1] = bf_hi(u[q]);
    }
#pragma unroll
    for (int j = 0; j < PL; ++j) { sum += v[j]; sq += v[j] * v[j]; }
#pragma unroll
    for (int o = 32; o >= 1; o >>= 1) {
        sum += __shfl_xor(sum, o);
        sq += __shfl_xor(sq, o);
    }
    float mean = sum * (1.0f / D);
    float var = sq * (1.0f / D) - mean * mean;
    float r = rsqrtf(var + 1e-5f);
    uint_t w[PL / 2];
#pragma unroll
    for (int q = 0; q < PL / 2; ++q) {
        int d = lane * PL + 2 * q;
        float a0 = (v[2 * q] - mean) * r * sc[d] + bi[d];
        float a1 = (v[2 * q + 1] - mean) * r * sc[d + 1] + bi[d + 1];
        w[q] = (uint_t)f2bf(a0) | ((uint_t)f2bf(a1) << 16);
    }
    ushort_t* op = out + (size_t)row * D + lane * PL;
    if (PL == 8) *(uint4*)op = *(uint4*)w;
    else *(uint2*)op = *(uint2*)w;
}

// ---------------- bf16 MFMA GEMM: 256x256 tile, 8 waves (4Mx2N), 2-stage dbuf ----------------
// A: MxK bf16 row-major, row stride lda. Wt: NxK bf16 (stride K). C = act(A@Wt^T+bias+res).
// grid = (N/256, M/256), XCD-swizzled. 512 thr = 8 waves; wave w: wr=w>>1 (rows wr*64..+64),
// wc=w&1 (cols wc*128..+128); acc[4][8] = 32 MFMA per K-32 step fed by 12 ds_read_b128.
// 2-stage double buffer: stage(t+1) -> vmcnt(4) -> barrier -> compute(t) -> barrier.
// __launch_bounds__(512) (NOT ,2): full 256-VGPR budget so acc[4][8]=128 stays in regs
// (r15's ",2" forced a 128-VGPR cap -> accumulator spilled to scratch -> 2x regression).
// Chunk swizzle (rule #21 both-sides). M%256==0, N%256==0, K%32==0.
template <int ACT>
__global__ __launch_bounds__(512) void k_gemm_mfma(
    const ushort_t* __restrict__ A, const ushort_t* __restrict__ Wt,
    const float* __restrict__ bias, const ushort_t* __restrict__ res,
    ushort_t* __restrict__ Cout, int M, int N, int K, int lda) {
    // 2 stages x (A 256x32 + B 256x32) u16 = 2 x 16384 u16 = 64KB; epilogue Cs[128][136] reuses
    __shared__ __align__(16) ushort_t smem[32768];

    const int t = threadIdx.x;
    // bijective XCD swizzle (m204)
    const int gx = gridDim.x;
    int flat = blockIdx.y * gx + blockIdx.x;
    int nwg = gx * gridDim.y;
    int q8 = nwg >> 3, r8 = nwg & 7;
    int xcd = flat & 7, loc = flat >> 3;
    int wg = (xcd < r8 ? xcd * (q8 + 1) : r8 * (q8 + 1) + (xcd - r8) * q8) + loc;
    const int bm = wg / gx, bn = wg % gx;

    const int lane = t & 63;
    const int wave = t >> 6;             // 0..7
    const int wr = wave >> 1, wc = wave & 1;
    const int l15 = lane & 15;
    const int g4 = lane >> 4;
    const int kq = (g4 ^ ((l15 >> 1) & 3)) * 8;   // swizzled read chunk

    const int srow = wave * 32 + (lane >> 2);     // staging row 0..255
    const int scol = ((lane & 3) ^ ((lane >> 3) & 3)) * 8;  // pre-swizzled source chunk
    const ushort_t* Ag = A + (size_t)(bm * 256 + srow) * lda + scol;
    const ushort_t* Bg = Wt + (size_t)(bn * 256 + srow) * K + scol;
    const int wb0 = wave * 1024;         // wave staging base (u16): (wave*32)*32

    // per-lane fragment read bases (u16): buffer offset added at use
    const ushort_t* Ard = smem + (wr * 64 + l15) * 32 + kq;
    const ushort_t* Brd = smem + 8192 + (wc * 128 + l15) * 32 + kq;

    f32x4 acc[4][8] = {};
    const int nt = K >> 5;

#define STAGE(tile, b)                                            \
    do {                                                          \
        int k0_ = (tile) << 5;                                    \
        ushort_t* Ab_ = smem + (b) * 16384;                       \
        gl_lds16(Ag + k0_, Ab_ + wb0);                            \
        gl_lds16(Ag + (size_t)16 * lda + k0_, Ab_ + wb0 + 512);   \
        gl_lds16(Bg + k0_, Ab_ + 8192 + wb0);                     \
        gl_lds16(Bg + (size_t)16 * K + k0_, Ab_ + 8192 + wb0 + 512); \
    } while (0)

    // prologue: stage tile 0 -> buf0
    STAGE(0, 0);

    for (int tt = 0; tt < nt; ++tt) {
        if (tt + 1 < nt) {
            STAGE(tt + 1, (tt + 1) & 1);
            asm volatile("s_waitcnt vmcnt(4)" ::: "memory");
        } else {
            asm volatile("s_waitcnt vmcnt(0)" ::: "memory");
        }
        __builtin_amdgcn_s_barrier();
        __builtin_amdgcn_sched_barrier(0);
        const int bo = (tt & 1) * 16384;
        short8 af[4], bfr[8];
#pragma unroll
        for (int m = 0; m < 4; ++m)
            af[m] = *(const short8*)(Ard + bo + m * 512);
#pragma unroll
        for (int n = 0; n < 8; ++n)
            bfr[n] = *(const short8*)(Brd + bo + n * 512);
        __builtin_amdgcn_s_setprio(1);
#pragma unroll
        for (int m = 0; m < 4; ++m)
#pragma unroll
            for (int n = 0; n < 8; ++n)
                acc[m][n] = __builtin_amdgcn_mfma_f32_16x16x32_bf16(af[m], bfr[n], acc[m][n], 0, 0, 0);
        __builtin_amdgcn_s_setprio(0);
        __builtin_amdgcn_sched_barrier(0);
        __builtin_amdgcn_s_barrier();
    }
#undef STAGE

    // ---- epilogue: 4 quadrant passes (hp = row half, cp = col half) through Cs[128][136] ----
    ushort_t* Cs = smem;
#pragma unroll
    for (int hp = 0; hp < 2; ++hp) {
#pragma unroll
        for (int cp = 0; cp < 2; ++cp) {
            if ((wave >> 2) == hp && (wave & 1) == cp) {
                const int erow0 = (wr & 1) * 64;
#pragma unroll
                for (int m = 0; m < 4; ++m)
#pragma unroll
                    for (int n = 0; n < 8; ++n)
#pragma unroll
                        for (int r = 0; r < 4; ++r) {
                            float v = acc[m][n][r];
                            float o = __shfl_xor(v, 1);
                            if (!(l15 & 1)) {
                                uint_t pk = cvtpk(v, o);
                                *(uint_t*)&Cs[(erow0 + m * 16 + g4 * 4 + r) * 136 + n * 16 + l15] = pk;
                            }
                        }
            }
            __builtin_amdgcn_s_barrier();
            const int row = t >> 2, q4 = t & 3;
            const int grow = bm * 256 + hp * 128 + row;
            const int gc0 = bn * 256 + cp * 128 + q4 * 32;
            const ushort_t* rres = res ? res + (size_t)grow * N + gc0 : (const ushort_t*)0;
            ushort_t* gout = Cout + (size_t)grow * N + gc0;
#pragma unroll
            for (int c = 0; c < 4; ++c) {
                uint4 pv = *(const uint4*)&Cs[row * 136 + q4 * 32 + c * 8];
                uint_t* pw = (uint_t*)&pv;
                float vv[8];
#pragma unroll
                for (int q = 0; q < 4; ++q) { vv[2 * q] = bf_lo(pw[q]); vv[2 * q + 1] = bf_hi(pw[q]); }
                if (bias) {
#pragma unroll
                    for (int j = 0; j < 8; ++j) vv[j] += bias[gc0 + c * 8 + j];
                }
                if (res) {
                    uint4 rv = *(const uint4*)(rres + c * 8);
                    uint_t* pr = (uint_t*)&rv;
#pragma unroll
                    for (int q = 0; q < 4; ++q) { vv[2 * q] += bf_lo(pr[q]); vv[2 * q + 1] += bf_hi(pr[q]); }
                }
                if (ACT == 1) {
#pragma unroll
                    for (int j = 0; j < 8; ++j) vv[j] = gelu_f(vv[j]);
                }
                uint4 ov;
                uint_t* po = (uint_t*)&ov;
#pragma unroll
                for (int q = 0; q < 4; ++q)
                    po[q] = cvtpk(vv[2 * q], vv[2 * q + 1]);
                *(uint4*)(gout + c * 8) = ov;
            }
            __builtin_amdgcn_s_barrier();
        }
    }
}

// ---------------- MFMA attention: block per (sequence, 4-head group) ----------------
// qkv bf16: rows (s*NT+n) stride 1536, cols [0,512)=q, [512,1024)=k, [1024,1536)=v.
// O is written IN-PLACE into the q-region. bias f32: [s][NT][NT].
template <int NT>
__global__ __launch_bounds__(256) void k_attn_mfma(
    ushort_t* __restrict__ qkv, const float* __restrict__ bias) {
    constexpr int NTP = (NT + 15) & ~15;  // 16 or 32
    constexpr int MT = NTP / 16;          // 1 or 2
    constexpr int QS = 72;                // q/k LDS row stride (u16)
    constexpr int VS = 40;                // vt/p LDS row stride (u16)
    __shared__ __align__(16) ushort_t smem[4 * NTP * QS * 2 + 4 * 64 * VS];
    ushort_t* Qs = smem;
    ushort_t* Ks = smem + 4 * NTP * QS;
    ushort_t* Vs = Ks + 4 * NTP * QS;
    ushort_t* Ps = smem;  // aliases Qs (dead after QK^T)

    const int s = blockIdx.x, hg = blockIdx.y;
    const int t = threadIdx.x;
    const int wave = t >> 6, lane = t & 63;
    const int l15 = lane & 15, g4 = lane >> 4;

    const ushort_t* qb = qkv + (size_t)s * NT * 1536 + hg * 256;
    for (int c = t; c < 64 * NT; c += 256) {
        int c8 = c & 7;
        int rem = c >> 3;
        int r = rem % NT;
        int ph = rem / NT;  // 0..7
        int h = ph & 3, p = ph >> 2;
        uint4 v = *(const uint4*)(qb + (size_t)r * 1536 + p * 512 + h * 64 + c8 * 8);
        ushort_t* dst = (p ? Ks : Qs) + (h * NTP + r) * QS + c8 * 8;
        *(uint4*)dst = v;
    }
    const ushort_t* vrow = qkv + (size_t)s * NT * 1536 + 1024 + hg * 256;
    for (int c = t; c < 4 * 64 * (32 - NT); c += 256) {
        int p = c % (32 - NT);
        int hd = c / (32 - NT);
        Vs[hd * VS + NT + p] = 0;
    }
    for (int c = t; c < 4 * NT * 8; c += 256) {
        int c8 = c & 7;
        int r = (c >> 3) % NT;
        int h = (c >> 3) / NT;
        uint4 v = *(const uint4*)(vrow + (size_t)r * 1536 + h * 64 + c8 * 8);
        const uint_t* pv = (const uint_t*)&v;
#pragma unroll
        for (int j = 0; j < 4; ++j) {
            Vs[(h * 64 + c8 * 8 + 2 * j) * VS + r] = (ushort_t)(pv[j] & 0xFFFFu);
            Vs[(h * 64 + c8 * 8 + 2 * j + 1) * VS + r] = (ushort_t)(pv[j] >> 16);
        }
    }
    __syncthreads();

    const int h = wave;
    const ushort_t* Qh = Qs + h * NTP * QS;
    const ushort_t* Kh = Ks + h * NTP * QS;
    const ushort_t* Vh = Vs + h * 64 * VS;
    ushort_t* Ph = Ps + h * NTP * VS;

    f32x4 sacc[MT][MT] = {};
#pragma unroll
    for (int ks = 0; ks < 2; ++ks) {
        short8 qf[MT], kf[MT];
#pragma unroll
        for (int m = 0; m < MT; ++m)
            qf[m] = *(const short8*)&Qh[(m * 16 + l15) * QS + ks * 32 + g4 * 8];
#pragma unroll
        for (int n = 0; n < MT; ++n)
            kf[n] = *(const short8*)&Kh[(n * 16 + l15) * QS + ks * 32 + g4 * 8];
#pragma unroll
        for (int m = 0; m < MT; ++m)
#pragma unroll
            for (int n = 0; n < MT; ++n)
                sacc[m][n] = __builtin_amdgcn_mfma_f32_16x16x32_bf16(qf[m], kf[n], sacc[m][n], 0, 0, 0);
    }

    const float* bp = bias + (size_t)s * NT * NT;
    float prv[MT][MT][4];
#pragma unroll
    for (int m = 0; m < MT; ++m) {
#pragma unroll
        for (int r = 0; r < 4; ++r) {
            int i = m * 16 + g4 * 4 + r;
            float sv[MT];
#pragma unroll
            for (int n = 0; n < MT; ++n) {
                int j = n * 16 + l15;
                sv[n] = (i < NT && j < NT) ? sacc[m][n][r] * 0.125f + bp[i * NT + j] : -1e30f;
            }
            float mx = sv[0];
            if (MT > 1) mx = fmaxf(mx, sv[MT - 1]);
#pragma unroll
            for (int o = 1; o < 16; o <<= 1) mx = fmaxf(mx, __shfl_xor(mx, o));
            float sum = 0.f;
#pragma unroll
            for (int n = 0; n < MT; ++n) {
                float e = (sv[n] > -1e29f) ? __expf(sv[n] - mx) : 0.f;
                prv[m][n][r] = e;
                sum += e;
            }
#pragma unroll
            for (int o = 1; o < 16; o <<= 1) sum += __shfl_xor(sum, o);
            float rs = sum > 0.f ? 1.0f / sum : 0.f;
#pragma unroll
            for (int n = 0; n < MT; ++n) prv[m][n][r] *= rs;
        }
    }
    __syncthreads();  // QK reads done before Ps (alias of Qs) written

    if (NTP == 16) {
        for (int z = lane; z < 16 * 8; z += 64) {
            int i = z >> 3, jw = z & 7;
            *(uint_t*)&Ph[i * VS + 16 + jw * 2] = 0;
        }
    }
#pragma unroll
    for (int m = 0; m < MT; ++m)
#pragma unroll
        for (int n = 0; n < MT; ++n)
#pragma unroll
            for (int r = 0; r < 4; ++r)
                Ph[(m * 16 + g4 * 4 + r) * VS + n * 16 + l15] = f2bf(prv[m][n][r]);
    __syncthreads();

    f32x4 oacc[MT][4] = {};
    {
        short8 pf[MT], vf[4];
#pragma unroll
        for (int m = 0; m < MT; ++m)
            pf[m] = *(const short8*)&Ph[(m * 16 + l15) * VS + g4 * 8];
#pragma unroll
        for (int nd = 0; nd < 4; ++nd)
            vf[nd] = *(const short8*)&Vh[(nd * 16 + l15) * VS + g4 * 8];
#pragma unroll
        for (int m = 0; m < MT; ++m)
#pragma unroll
            for (int nd = 0; nd < 4; ++nd)
                oacc[m][nd] = __builtin_amdgcn_mfma_f32_16x16x32_bf16(pf[m], vf[nd], oacc[m][nd], 0, 0, 0);
    }

    // ---- store O in-place into the q-region (row stride 1536) ----
    ushort_t* Ob = qkv + (size_t)s * NT * 1536 + hg * 256 + h * 64;
#pragma unroll
    for (int m = 0; m < MT; ++m)
#pragma unroll
        for (int r = 0; r < 4; ++r) {
            int i = m * 16 + g4 * 4 + r;
            if (i < NT) {
#pragma unroll
                for (int nd = 0; nd < 4; ++nd)
                    Ob[(size_t)i * 1536 + nd * 16 + l15] = f2bf(oacc[m][nd][r]);
            }
        }
}

// ---------------- decoder token assembly ----------------
__global__ void k_build_dec(const ushort_t* __restrict__ dec_tok, const float* __restrict__ mask_token,
                            const float* __restrict__ dec_pos, const int* __restrict__ mi,
                            ushort_t* __restrict__ Xd, float* __restrict__ out0, int base) {
    int s = blockIdx.x;
    int g = base + s;
    int t = threadIdx.x;
    for (int idx = t; idx < N_SEQ * DD; idx += 256) {
        int i = idx / DD, d = idx % DD;
        float v;
        if (i < NM) {
            int m = mi[g * NM + i];
            v = mask_token[d] + dec_pos[(size_t)m * DD + d];
        } else {
            v = bf2f(dec_tok[((size_t)s * NU + (i - NM)) * DD + d]);
        }
        Xd[((size_t)s * N_SEQ + i) * DD + d] = f2bf(v);
        out0[((size_t)g * N_SEQ + i) * DD + d] = v;
    }
}

// ---------------- prediction head + loss ----------------
__global__ void k_pred(const ushort_t* __restrict__ Xd, const int* __restrict__ mi,
                       const float* __restrict__ pW, const float* __restrict__ pb,
                       const float* __restrict__ mn, float* __restrict__ out_pred,
                       float* __restrict__ loss, int base, int Bc) {
    int tid = blockIdx.x * 256 + threadIdx.x;
    int total = Bc * NM * NDIM;
    float part = 0.f;
    if (tid < total) {
        int c = tid % NDIM;
        int r = tid / NDIM;
        int i = r % NM;
        int s = r / NM;
        int g = base + s;
        int m = mi[g * NM + i];
        const ushort_t* row = Xd + ((size_t)s * N_SEQ + m) * DD;
        float acc = pb[c];
        for (int k = 0; k < DD; ++k) acc += bf2f(row[k]) * pW[k * NDIM + c];
        out_pred[((size_t)g * NM + i) * NDIM + c] = acc;
        float d = acc - mn[((size_t)g * NM + i) * NDIM + c];
        part = d * d;
    }
    __shared__ float red[256];
    red[threadIdx.x] = part;
    __syncthreads();
    for (int o = 128; o > 0; o >>= 1) {
        if (threadIdx.x < o) red[threadIdx.x] += red[threadIdx.x + o];
        __syncthreads();
    }
    if (threadIdx.x == 0) atomicAdd(loss, red[0]);
}

// ---------------- host ----------------
extern "C" void kernel_launch(void* const* d_in, const int* in_sizes, int n_in,
                              void* d_out, int out_size, void* d_ws, size_t ws_size,
                              hipStream_t stream) {
    const float* x       = (const float*)d_in[0];
    const float* a       = (const float*)d_in[1];
    const int*   mi      = (const int*)d_in[2];
    const int*   ui      = (const int*)d_in[3];
    const float* W_emb   = (const float*)d_in[4];
    const float* b_emb   = (const float*)d_in[5];
    const float* pos_emb = (const float*)d_in[6];
    const float* e_ln1_s = (const float*)d_in[7];
    const float* e_ln1_b = (const float*)d_in[8];
    const float* e_Wqkv  = (const float*)d_in[9];
    const float* e_Wo    = (const float*)d_in[10];
    const float* e_bo    = (const float*)d_in[11];
    const float* e_ln2_s = (const float*)d_in[12];
    const float* e_ln2_b = (const float*)d_in[13];
    const float* e_W1    = (const float*)d_in[14];
    const float* e_b1    = (const float*)d_in[15];
    const float* e_W2    = (const float*)d_in[16];
    const float* e_b2    = (const float*)d_in[17];
    const float* e2d_W   = (const float*)d_in[18];
    const float* e2d_b   = (const float*)d_in[19];
    const float* mask_tok= (const float*)d_in[20];
    const float* dec_pos = (const float*)d_in[21];
    const float* d_ln1_s = (const float*)d_in[22];
    const float* d_ln1_b = (const float*)d_in[23];
    const float* d_Wqkv  = (const float*)d_in[24];
    const float* d_Wo    = (const float*)d_in[25];
    const float* d_bo    = (const float*)d_in[26];
    const float* d_ln2_s = (const float*)d_in[27];
    const float* d_ln2_b = (const float*)d_in[28];
    const float* d_W1    = (const float*)d_in[29];
    const float* d_b1    = (const float*)d_in[30];
    const float* d_W2    = (const float*)d_in[31];
    const float* d_b2    = (const float*)d_in[32];
    const float* pred_W  = (const float*)d_in[33];
    const float* pred_b  = (const float*)d_in[34];

    float* out0 = (float*)d_out;
    float* out1 = out0 + (size_t)B_TOT * N_SEQ * DD;
    float* out2 = out1 + (size_t)B_TOT * NM * NDIM;
    float* out3 = out2 + (size_t)B_TOT * NM;
    float* out4 = out3 + (size_t)B_TOT * NM * NDIM;

    // ---- workspace layout ----
    char* wp = (char*)d_ws;
    size_t off = 0;
    auto alloc = [&](size_t bytes) {
        size_t o = off;
        off = (off + bytes + 255) & ~(size_t)255;
        return (void*)(wp + o);
    };
    float* loss_acc = (float*)alloc(64 * 4);
    ushort_t* wt_eqkv = (ushort_t*)alloc((size_t)2 * 1536 * 512 * 2);
    ushort_t* wt_ewo  = (ushort_t*)alloc((size_t)2 * 512 * 512 * 2);
    ushort_t* wt_ew1  = (ushort_t*)alloc((size_t)2 * 2048 * 512 * 2);
    ushort_t* wt_ew2  = (ushort_t*)alloc((size_t)2 * 512 * 2048 * 2);
    ushort_t* wt_dqkv = (ushort_t*)alloc((size_t)1536 * 256 * 2);
    ushort_t* wt_dwo  = (ushort_t*)alloc((size_t)256 * 512 * 2);
    ushort_t* wt_dw1  = (ushort_t*)alloc((size_t)1024 * 256 * 2);
    ushort_t* wt_dw2  = (ushort_t*)alloc((size_t)256 * 1024 * 2);
    ushort_t* wt_e2d  = (ushort_t*)alloc((size_t)256 * 512 * 2);
    size_t fixed_bytes = off;

    // per-seq bytes: bf16 (X 7168 + H 7168 + QKV 43008) + f32 ua 196.
    // Dbuf aliases the head of QKVbuf (QKV dead when e2d writes; dqkv after build_dec).
    const size_t per_seq = 2 * (7168 + 7168 + 43008) + 4 * 196;
    int Bc = B_TOT;
    while (Bc > 128 && fixed_bytes + (size_t)Bc * per_seq + 8192 > ws_size) Bc >>= 1;

    ushort_t* Xbuf   = (ushort_t*)alloc((size_t)Bc * 7168 * 2);
    float*    uabuf  = (float*)alloc((size_t)Bc * 196 * 4);
    ushort_t* Hbuf   = (ushort_t*)alloc((size_t)Bc * 7168 * 2);
    ushort_t* QKVbuf = (ushort_t*)alloc((size_t)Bc * 43008 * 2);
    ushort_t* Dbuf   = QKVbuf;  // alias (see above)

    k_zero<<<1, 64, 0, stream>>>(loss_acc);

    // ---- weight conversion (once per launch) ----
    for (int l = 0; l < 2; ++l) {
        k_wconv<<<dim3(1536 / 32, 512 / 32), 256, 0, stream>>>(e_Wqkv + (size_t)l * 512 * 1536, wt_eqkv + (size_t)l * 1536 * 512, 512, 1536);
        k_wconv<<<dim3(512 / 32, 512 / 32), 256, 0, stream>>>(e_Wo + (size_t)l * 512 * 512, wt_ewo + (size_t)l * 512 * 512, 512, 512);
        k_wconv<<<dim3(2048 / 32, 512 / 32), 256, 0, stream>>>(e_W1 + (size_t)l * 512 * 2048, wt_ew1 + (size_t)l * 2048 * 512, 512, 2048);
        k_wconv<<<dim3(512 / 32, 2048 / 32), 256, 0, stream>>>(e_W2 + (size_t)l * 2048 * 512, wt_ew2 + (size_t)l * 512 * 2048, 2048, 512);
    }
    k_wconv<<<dim3(1536 / 32, 256 / 32), 256, 0, stream>>>(d_Wqkv, wt_dqkv, 256, 1536);
    k_wconv<<<dim3(256 / 32, 512 / 32), 256, 0, stream>>>(d_Wo, wt_dwo, 512, 256);
    k_wconv<<<dim3(1024 / 32, 256 / 32), 256, 0, stream>>>(d_W1, wt_dw1, 256, 1024);
    k_wconv<<<dim3(256 / 32, 1024 / 32), 256, 0, stream>>>(d_W2, wt_dw2, 1024, 256);
    k_wconv<<<dim3(256 / 32, 512 / 32), 256, 0, stream>>>(e2d_W, wt_e2d, 512, 256);

    const int nchunk = B_TOT / Bc;
    for (int c = 0; c < nchunk; ++c) {
        int base = c * Bc;
        int M = Bc * NU;
        int Md = Bc * N_SEQ;

        k_embed<<<Bc, 256, 0, stream>>>(x, a, mi, ui, W_emb, b_emb, pos_emb,
                                        Xbuf, uabuf, out1, out2, base);
        // ---- encoder ----
        for (int l = 0; l < 2; ++l) {
            k_ln<ED><<<M / 4, 256, 0, stream>>>(Xbuf, Hbuf, e_ln1_s + l * ED, e_ln1_b + l * ED, M);
            k_gemm_mfma<0><<<dim3(1536 / 256, M / 256), 512, 0, stream>>>(
                Hbuf, wt_eqkv + (size_t)l * 1536 * 512, nullptr, nullptr, QKVbuf, M, 1536, ED, ED);
            k_attn_mfma<NU><<<dim3(Bc, 2), 256, 0, stream>>>(QKVbuf, uabuf);
            k_gemm_mfma<0><<<dim3(ED / 256, M / 256), 512, 0, stream>>>(
                QKVbuf, wt_ewo + (size_t)l * 512 * 512, e_bo + l * ED, Xbuf, Xbuf, M, ED, 512, 1536);
            k_ln<ED><<<M / 4, 256, 0, stream>>>(Xbuf, Hbuf, e_ln2_s + l * ED, e_ln2_b + l * ED, M);
            k_gemm_mfma<1><<<dim3(EMLP / 256, M / 256), 512, 0, stream>>>(
                Hbuf, wt_ew1 + (size_t)l * 2048 * 512, e_b1 + l * EMLP, nullptr, QKVbuf, M, EMLP, ED, ED);
            k_gemm_mfma<0><<<dim3(ED / 256, M / 256), 512, 0, stream>>>(
                QKVbuf, wt_ew2 + (size_t)l * 512 * 2048, e_b2 + l * ED, Xbuf, Xbuf, M, ED, EMLP, EMLP);
        }
        // ---- encoder -> decoder ----
        k_gemm_mfma<0><<<dim3(DD / 256, M / 256), 512, 0, stream>>>(
            Xbuf, wt_e2d, e2d_b, nullptr, Dbuf, M, DD, ED, ED);
        k_build_dec<<<Bc, 256, 0, stream>>>(Dbuf, mask_tok, dec_pos, mi, Xbuf, out0, base);
        // ---- decoder ----
        k_ln<DD><<<Md / 4, 256, 0, stream>>>(Xbuf, Hbuf, d_ln1_s, d_ln1_b, Md);
        k_gemm_mfma<0><<<dim3(1536 / 256, Md / 256), 512, 0, stream>>>(
            Hbuf, wt_dqkv, nullptr, nullptr, QKVbuf, Md, 1536, DD, DD);
        k_attn_mfma<N_SEQ><<<dim3(Bc, 2), 256, 0, stream>>>(QKVbuf, a + (size_t)base * N_SEQ * N_SEQ);
        k_gemm_mfma<0><<<dim3(DD / 256, Md / 256), 512, 0, stream>>>(
            QKVbuf, wt_dwo, d_bo, Xbuf, Xbuf, Md, DD, 512, 1536);
        k_ln<DD><<<Md / 4, 256, 0, stream>>>(Xbuf, Hbuf, d_ln2_s, d_ln2_b, Md);
        k_gemm_mfma<1><<<dim3(DMLP / 256, Md / 256), 512, 0, stream>>>(
            Hbuf, wt_dw1, d_b1, nullptr, QKVbuf, Md, DMLP, DD, DD);
        k_gemm_mfma<0><<<dim3(DD / 256, Md / 256), 512, 0, stream>>>(
            QKVbuf, wt_dw2, d_b2, Xbuf, Xbuf, Md, DD, DMLP, DMLP);
        // ---- prediction + loss ----
        int tot = Bc * NM * NDIM;
        k_pred<<<(tot + 255) / 256, 256, 0, stream>>>(
            Xbuf, mi, pred_W, pred_b, out1, out3, loss_acc, base, Bc);
    }
    k_final<<<1, 1, 0, stream>>>(loss_acc, out4);
}

// Round 17
// 2647.136 us; speedup vs baseline: 1.5554x; 1.5510x over previous
//
#include <hip/hip_runtime.h>
#include <math.h>

#define B_TOT 4096
#define N_SEQ 28
#define NDIM 3
#define ED 512
#define DD 256
#define NH 8
#define DHD 64
#define EMLP 2048
#define DMLP 1024
#define NM 14
#define NU 14

typedef __attribute__((ext_vector_type(8))) short short8;
typedef __attribute__((ext_vector_type(4))) float f32x4;
typedef unsigned short ushort_t;
typedef unsigned int uint_t;

// ---------------- helpers ----------------
__device__ __forceinline__ float gelu_f(float x) {
    float t = 0.7978845608028654f * (x + 0.044715f * x * x * x);
    float e = __expf(2.0f * t);
    float th = 1.0f - 2.0f / (e + 1.0f);   // tanh(t), overflow-safe
    return 0.5f * x * (1.0f + th);
}
__device__ __forceinline__ ushort_t f2bf(float f) {
    union { float f; uint_t u; } c; c.f = f;
    uint_t u = c.u;
    return (ushort_t)((u + 0x7FFFu + ((u >> 16) & 1u)) >> 16);
}
__device__ __forceinline__ float bf2f(ushort_t h) {
    union { uint_t u; float f; } c; c.u = ((uint_t)h) << 16;
    return c.f;
}
__device__ __forceinline__ float bf_lo(uint_t u) {
    union { uint_t u; float f; } c; c.u = u << 16;
    return c.f;
}
__device__ __forceinline__ float bf_hi(uint_t u) {
    union { uint_t u; float f; } c; c.u = u & 0xFFFF0000u;
    return c.f;
}
// packed f32x2 -> bf16x2 (RNE), single VALU op
__device__ __forceinline__ uint_t cvtpk(float lo, float hi) {
    uint_t r;
    asm volatile("v_cvt_pk_bf16_f32 %0, %1, %2" : "=v"(r) : "v"(lo), "v"(hi));
    return r;
}
__device__ __forceinline__ void gl_lds16(const ushort_t* g, ushort_t* l) {
    __builtin_amdgcn_global_load_lds(
        (const __attribute__((address_space(1))) unsigned int*)g,
        (__attribute__((address_space(3))) unsigned int*)l, 16, 0, 0);
}

// ---------------- zero / finalize ----------------
__global__ void k_zero(float* p) { p[threadIdx.x] = 0.0f; }
__global__ void k_final(const float* acc, float* out) {
    out[0] = acc[0] * (1.0f / (float)(B_TOT * NM * NDIM));
}

// ---------------- weight transpose + bf16 convert: Wt[n][k] = bf(W[k][n]) ----------------
__global__ void k_wconv(const float* __restrict__ W, ushort_t* __restrict__ Wt, int K, int N) {
    __shared__ float tile[32][33];
    int n0 = blockIdx.x * 32, k0 = blockIdx.y * 32;
    int tr = threadIdx.x >> 5, tc = threadIdx.x & 31;  // 8 x 32
#pragma unroll
    for (int i = 0; i < 4; ++i)
        tile[tr + i * 8][tc] = W[(size_t)(k0 + tr + i * 8) * N + n0 + tc];
    __syncthreads();
#pragma unroll
    for (int i = 0; i < 4; ++i)
        Wt[(size_t)(n0 + tr + i * 8) * K + k0 + tc] = f2bf(tile[tc][tr + i * 8]);
}

// ---------------- embed + gathers (bf16 X out) ----------------
__global__ void k_embed(const float* __restrict__ x, const float* __restrict__ a,
                        const int* __restrict__ mi, const int* __restrict__ ui,
                        const float* __restrict__ W_emb, const float* __restrict__ b_emb,
                        const float* __restrict__ pos_emb,
                        ushort_t* __restrict__ X, float* __restrict__ ua,
                        float* __restrict__ out_mn, float* __restrict__ out_midx,
                        int base) {
    int s = blockIdx.x;
    int g = base + s;
    int t = threadIdx.x;
    for (int i = 0; i < NU; ++i) {
        int u = ui[g * NU + i];
        float x0 = x[((size_t)g * N_SEQ + u) * NDIM + 0];
        float x1 = x[((size_t)g * N_SEQ + u) * NDIM + 1];
        float x2 = x[((size_t)g * N_SEQ + u) * NDIM + 2];
        for (int d = t; d < ED; d += 256) {
            X[((size_t)s * NU + i) * ED + d] = f2bf(
                x0 * W_emb[d] + x1 * W_emb[ED + d] + x2 * W_emb[2 * ED + d]
                + b_emb[d] + pos_emb[(size_t)u * ED + d]);
        }
    }
    for (int idx = t; idx < NU * NU; idx += 256) {
        int i = idx / NU, j = idx % NU;
        int uii = ui[g * NU + i], ujj = ui[g * NU + j];
        ua[(size_t)s * NU * NU + idx] = a[(size_t)g * N_SEQ * N_SEQ + (size_t)uii * N_SEQ + ujj];
    }
    for (int idx = t; idx < NM * NDIM; idx += 256) {
        int i = idx / NDIM, c = idx % NDIM;
        int m = mi[g * NM + i];
        out_mn[((size_t)g * NM + i) * NDIM + c] = x[((size_t)g * N_SEQ + m) * NDIM + c];
    }
    for (int i = t; i < NM; i += 256) {
        out_midx[(size_t)g * NM + i] = (float)mi[g * NM + i];
    }
}

// ---------------- layernorm: bf16 in -> bf16 out ----------------
template <int D>
__global__ void k_ln(const ushort_t* __restrict__ in, ushort_t* __restrict__ out,
                     const float* __restrict__ sc, const float* __restrict__ bi, int M) {
    int wave = threadIdx.x >> 6;
    int lane = threadIdx.x & 63;
    int row = blockIdx.x * 4 + wave;
    if (row >= M) return;
    constexpr int PL = D / 64;  // 8 (ED) or 4 (DD)
    const ushort_t* rp = in + (size_t)row * D + lane * PL;
    uint_t u[PL / 2];
    if (PL == 8) *(uint4*)u = *(const uint4*)rp;
    else *(uint2*)u = *(const uint2*)rp;
    float v[PL];
    float sum = 0.f, sq = 0.f;
#pragma unroll
    for (int q = 0; q < PL / 2; ++q) {
        v[2 * q] = bf_lo(u[q]);
        v[2 * q + 1] = bf_hi(u[q]);
    }
#pragma unroll
    for (int j = 0; j < PL; ++j) { sum += v[j]; sq += v[j] * v[j]; }
#pragma unroll
    for (int o = 32; o >= 1; o >>= 1) {
        sum += __shfl_xor(sum, o);
        sq += __shfl_xor(sq, o);
    }
    float mean = sum * (1.0f / D);
    float var = sq * (1.0f / D) - mean * mean;
    float r = rsqrtf(var + 1e-5f);
    uint_t w[PL / 2];
#pragma unroll
    for (int q = 0; q < PL / 2; ++q) {
        int d = lane * PL + 2 * q;
        float a0 = (v[2 * q] - mean) * r * sc[d] + bi[d];
        float a1 = (v[2 * q + 1] - mean) * r * sc[d + 1] + bi[d + 1];
        w[q] = (uint_t)f2bf(a0) | ((uint_t)f2bf(a1) << 16);
    }
    ushort_t* op = out + (size_t)row * D + lane * PL;
    if (PL == 8) *(uint4*)op = *(uint4*)w;
    else *(uint2*)op = *(uint2*)w;
}

// ---------------- bf16 MFMA GEMM: 128x128, 3-stage 1-barrier (round-12 structure) ----------------
// A: MxK bf16 row-major with row stride lda. Wt: NxK bf16 row-major (stride K).
// C = act(A@Wt^T + bias + res), bf16, stride N. grid = (N/128, M/128), XCD-swizzled.
// 256 thr = 4 waves (2x2), each wave 64x64. 4 global_load_lds per stage, 2 stages in
// flight -> vmcnt(4) at the wait (T4: N = loads_per_stage x stages-ahead).
// Chunk swizzle (rule #21 both-sides): source scol ^= (lane>>3)&3, read kq ^= (l15>>1)&3.
template <int ACT>
__global__ __launch_bounds__(256) void k_gemm_mfma(
    const ushort_t* __restrict__ A, const ushort_t* __restrict__ Wt,
    const float* __restrict__ bias, const ushort_t* __restrict__ res,
    ushort_t* __restrict__ Cout, int M, int N, int K, int lda) {
    // 3 x (A 4096 + B 4096) u16 = 48KB staging; epilogue Cs[128][136] (34816B) reuses
    __shared__ __align__(16) ushort_t smem[24576];

    const int t = threadIdx.x;
    // bijective XCD swizzle (m204)
    const int gx = gridDim.x;
    int flat = blockIdx.y * gx + blockIdx.x;
    int nwg = gx * gridDim.y;
    int q8 = nwg >> 3, r8 = nwg & 7;
    int xcd = flat & 7, loc = flat >> 3;
    int wg = (xcd < r8 ? xcd * (q8 + 1) : r8 * (q8 + 1) + (xcd - r8) * q8) + loc;
    const int bm = wg / gx, bn = wg % gx;

    const int lane = t & 63;
    const int wave = t >> 6;
    const int wr = wave >> 1, wc = wave & 1;
    const int l15 = lane & 15;
    const int g4 = lane >> 4;
    const int kq = (g4 ^ ((l15 >> 1) & 3)) * 8;   // swizzled read chunk

    const int srow = wave * 32 + (lane >> 2);
    const int scol = ((lane & 3) ^ ((lane >> 3) & 3)) * 8;  // pre-swizzled source chunk
    const ushort_t* Ag = A + (size_t)(bm * 128 + srow) * lda + scol;
    const ushort_t* Bg = Wt + (size_t)(bn * 128 + srow) * K + scol;
    const int wb0 = (wave * 32) * 32;        // wave's LDS staging base (u16)
    const int wb1 = (wave * 32 + 16) * 32;

    f32x4 acc[4][4] = {};
    const int nt = K >> 5;

#define STAGE(tile, idx)                                          \
    do {                                                          \
        int k0_ = (tile) << 5;                                    \
        ushort_t* Ab_ = smem + (idx) * 8192;                      \
        ushort_t* Bb_ = Ab_ + 4096;                               \
        gl_lds16(Ag + k0_, Ab_ + wb0);                            \
        gl_lds16(Ag + (size_t)16 * lda + k0_, Ab_ + wb1);         \
        gl_lds16(Bg + k0_, Bb_ + wb0);                            \
        gl_lds16(Bg + (size_t)16 * K + k0_, Bb_ + wb1);           \
    } while (0)

    // prologue: stage tiles 0,1
    STAGE(0, 0);
    STAGE(1, 1);

    int cur = 0;
    for (int tt = 0; tt < nt; ++tt) {
        if (tt + 1 < nt) asm volatile("s_waitcnt vmcnt(4)" ::: "memory");
        else             asm volatile("s_waitcnt vmcnt(0)" ::: "memory");
        __builtin_amdgcn_s_barrier();
        __builtin_amdgcn_sched_barrier(0);
        if (tt + 2 < nt) {
            int nidx = cur + 2; if (nidx >= 3) nidx -= 3;
            STAGE(tt + 2, nidx);
        }
        const ushort_t* Ac = smem + cur * 8192;
        const ushort_t* Bc = Ac + 4096;
        short8 af[4], bfr[4];
#pragma unroll
        for (int m = 0; m < 4; ++m)
            af[m] = *(const short8*)&Ac[(wr * 64 + m * 16 + l15) * 32 + kq];
#pragma unroll
        for (int n = 0; n < 4; ++n)
            bfr[n] = *(const short8*)&Bc[(wc * 64 + n * 16 + l15) * 32 + kq];
        __builtin_amdgcn_s_setprio(1);
#pragma unroll
        for (int m = 0; m < 4; ++m)
#pragma unroll
            for (int n = 0; n < 4; ++n)
                acc[m][n] = __builtin_amdgcn_mfma_f32_16x16x32_bf16(af[m], bfr[n], acc[m][n], 0, 0, 0);
        __builtin_amdgcn_s_setprio(0);
        if (++cur == 3) cur = 0;
    }
#undef STAGE

    __builtin_amdgcn_sched_barrier(0);
    __builtin_amdgcn_s_barrier();   // all waves done with LDS reads before Cs reuse

    // ---- epilogue: acc -> Cs (bf16, packed col-pairs), then coalesced out ----
    ushort_t* Cs = smem;  // [128][136]
    const int erow0 = wr * 64, ecol0 = wc * 64;
#pragma unroll
    for (int m = 0; m < 4; ++m)
#pragma unroll
        for (int n = 0; n < 4; ++n)
#pragma unroll
            for (int r = 0; r < 4; ++r) {
                float v = acc[m][n][r];
                float o = __shfl_xor(v, 1);
                if (!(l15 & 1)) {
                    uint_t pk = cvtpk(v, o);
                    *(uint_t*)&Cs[(erow0 + m * 16 + g4 * 4 + r) * 136 + ecol0 + n * 16 + l15] = pk;
                }
            }
    __builtin_amdgcn_s_barrier();

    const int row = t >> 1, half = t & 1;
    const int grow = bm * 128 + row;
    const int gc0 = bn * 128 + half * 64;
    const ushort_t* rres = res ? res + (size_t)grow * N + gc0 : (const ushort_t*)0;
    ushort_t* gout = Cout + (size_t)grow * N + gc0;
#pragma unroll
    for (int c = 0; c < 8; ++c) {
        uint4 pv = *(const uint4*)&Cs[row * 136 + half * 64 + c * 8];
        uint_t* pw = (uint_t*)&pv;
        float vv[8];
#pragma unroll
        for (int q = 0; q < 4; ++q) { vv[2 * q] = bf_lo(pw[q]); vv[2 * q + 1] = bf_hi(pw[q]); }
        if (bias) {
#pragma unroll
            for (int j = 0; j < 8; ++j) vv[j] += bias[gc0 + c * 8 + j];
        }
        if (res) {
            uint4 rv = *(const uint4*)(rres + c * 8);
            uint_t* pr = (uint_t*)&rv;
#pragma unroll
            for (int q = 0; q < 4; ++q) { vv[2 * q] += bf_lo(pr[q]); vv[2 * q + 1] += bf_hi(pr[q]); }
        }
        if (ACT == 1) {
#pragma unroll
            for (int j = 0; j < 8; ++j) vv[j] = gelu_f(vv[j]);
        }
        uint4 ov;
        uint_t* po = (uint_t*)&ov;
#pragma unroll
        for (int q = 0; q < 4; ++q)
            po[q] = cvtpk(vv[2 * q], vv[2 * q + 1]);
        *(uint4*)(gout + c * 8) = ov;
    }
}

// ---------------- MFMA attention: block per (sequence, 4-head group) ----------------
// qkv bf16: rows (s*NT+n) stride 1536, cols [0,512)=q, [512,1024)=k, [1024,1536)=v.
// O is written IN-PLACE into the q-region (cols hg*256 + h*64 + d) — q is dead
// after QK^T and each block touches only its own hg half. bias f32: [s][NT][NT].
template <int NT>
__global__ __launch_bounds__(256) void k_attn_mfma(
    ushort_t* __restrict__ qkv, const float* __restrict__ bias) {
    constexpr int NTP = (NT + 15) & ~15;  // 16 or 32
    constexpr int MT = NTP / 16;          // 1 or 2
    constexpr int QS = 72;                // q/k LDS row stride (u16)
    constexpr int VS = 40;                // vt/p LDS row stride (u16)
    __shared__ __align__(16) ushort_t smem[4 * NTP * QS * 2 + 4 * 64 * VS];
    ushort_t* Qs = smem;
    ushort_t* Ks = smem + 4 * NTP * QS;
    ushort_t* Vs = Ks + 4 * NTP * QS;
    ushort_t* Ps = smem;  // aliases Qs (dead after QK^T)

    const int s = blockIdx.x, hg = blockIdx.y;
    const int t = threadIdx.x;
    const int wave = t >> 6, lane = t & 63;
    const int l15 = lane & 15, g4 = lane >> 4;

    const ushort_t* qb = qkv + (size_t)s * NT * 1536 + hg * 256;
    for (int c = t; c < 64 * NT; c += 256) {
        int c8 = c & 7;
        int rem = c >> 3;
        int r = rem % NT;
        int ph = rem / NT;  // 0..7
        int h = ph & 3, p = ph >> 2;
        uint4 v = *(const uint4*)(qb + (size_t)r * 1536 + p * 512 + h * 64 + c8 * 8);
        ushort_t* dst = (p ? Ks : Qs) + (h * NTP + r) * QS + c8 * 8;
        *(uint4*)dst = v;
    }
    const ushort_t* vrow = qkv + (size_t)s * NT * 1536 + 1024 + hg * 256;
    for (int c = t; c < 4 * 64 * (32 - NT); c += 256) {
        int p = c % (32 - NT);
        int hd = c / (32 - NT);
        Vs[hd * VS + NT + p] = 0;
    }
    for (int c = t; c < 4 * NT * 8; c += 256) {
        int c8 = c & 7;
        int r = (c >> 3) % NT;
        int h = (c >> 3) / NT;
        uint4 v = *(const uint4*)(vrow + (size_t)r * 1536 + h * 64 + c8 * 8);
        const uint_t* pv = (const uint_t*)&v;
#pragma unroll
        for (int j = 0; j < 4; ++j) {
            Vs[(h * 64 + c8 * 8 + 2 * j) * VS + r] = (ushort_t)(pv[j] & 0xFFFFu);
            Vs[(h * 64 + c8 * 8 + 2 * j + 1) * VS + r] = (ushort_t)(pv[j] >> 16);
        }
    }
    __syncthreads();

    const int h = wave;
    const ushort_t* Qh = Qs + h * NTP * QS;
    const ushort_t* Kh = Ks + h * NTP * QS;
    const ushort_t* Vh = Vs + h * 64 * VS;
    ushort_t* Ph = Ps + h * NTP * VS;

    f32x4 sacc[MT][MT] = {};
#pragma unroll
    for (int ks = 0; ks < 2; ++ks) {
        short8 qf[MT], kf[MT];
#pragma unroll
        for (int m = 0; m < MT; ++m)
            qf[m] = *(const short8*)&Qh[(m * 16 + l15) * QS + ks * 32 + g4 * 8];
#pragma unroll
        for (int n = 0; n < MT; ++n)
            kf[n] = *(const short8*)&Kh[(n * 16 + l15) * QS + ks * 32 + g4 * 8];
#pragma unroll
        for (int m = 0; m < MT; ++m)
#pragma unroll
            for (int n = 0; n < MT; ++n)
                sacc[m][n] = __builtin_amdgcn_mfma_f32_16x16x32_bf16(qf[m], kf[n], sacc[m][n], 0, 0, 0);
    }

    const float* bp = bias + (size_t)s * NT * NT;
    float prv[MT][MT][4];
#pragma unroll
    for (int m = 0; m < MT; ++m) {
#pragma unroll
        for (int r = 0; r < 4; ++r) {
            int i = m * 16 + g4 * 4 + r;
            float sv[MT];
#pragma unroll
            for (int n = 0; n < MT; ++n) {
                int j = n * 16 + l15;
                sv[n] = (i < NT && j < NT) ? sacc[m][n][r] * 0.125f + bp[i * NT + j] : -1e30f;
            }
            float mx = sv[0];
            if (MT > 1) mx = fmaxf(mx, sv[MT - 1]);
#pragma unroll
            for (int o = 1; o < 16; o <<= 1) mx = fmaxf(mx, __shfl_xor(mx, o));
            float sum = 0.f;
#pragma unroll
            for (int n = 0; n < MT; ++n) {
                float e = (sv[n] > -1e29f) ? __expf(sv[n] - mx) : 0.f;
                prv[m][n][r] = e;
                sum += e;
            }
#pragma unroll
            for (int o = 1; o < 16; o <<= 1) sum += __shfl_xor(sum, o);
            float rs = sum > 0.f ? 1.0f / sum : 0.f;
#pragma unroll
            for (int n = 0; n < MT; ++n) prv[m][n][r] *= rs;
        }
    }
    __syncthreads();  // QK reads done before Ps (alias of Qs) written

    if (NTP == 16) {
        for (int z = lane; z < 16 * 8; z += 64) {
            int i = z >> 3, jw = z & 7;
            *(uint_t*)&Ph[i * VS + 16 + jw * 2] = 0;
        }
    }
#pragma unroll
    for (int m = 0; m < MT; ++m)
#pragma unroll
        for (int n = 0; n < MT; ++n)
#pragma unroll
            for (int r = 0; r < 4; ++r)
                Ph[(m * 16 + g4 * 4 + r) * VS + n * 16 + l15] = f2bf(prv[m][n][r]);
    __syncthreads();

    f32x4 oacc[MT][4] = {};
    {
        short8 pf[MT], vf[4];
#pragma unroll
        for (int m = 0; m < MT; ++m)
            pf[m] = *(const short8*)&Ph[(m * 16 + l15) * VS + g4 * 8];
#pragma unroll
        for (int nd = 0; nd < 4; ++nd)
            vf[nd] = *(const short8*)&Vh[(nd * 16 + l15) * VS + g4 * 8];
#pragma unroll
        for (int m = 0; m < MT; ++m)
#pragma unroll
            for (int nd = 0; nd < 4; ++nd)
                oacc[m][nd] = __builtin_amdgcn_mfma_f32_16x16x32_bf16(pf[m], vf[nd], oacc[m][nd], 0, 0, 0);
    }

    // ---- store O in-place into the q-region (row stride 1536) ----
    ushort_t* Ob = qkv + (size_t)s * NT * 1536 + hg * 256 + h * 64;
#pragma unroll
    for (int m = 0; m < MT; ++m)
#pragma unroll
        for (int r = 0; r < 4; ++r) {
            int i = m * 16 + g4 * 4 + r;
            if (i < NT) {
#pragma unroll
                for (int nd = 0; nd < 4; ++nd)
                    Ob[(size_t)i * 1536 + nd * 16 + l15] = f2bf(oacc[m][nd][r]);
            }
        }
}

// ---------------- decoder token assembly ----------------
__global__ void k_build_dec(const ushort_t* __restrict__ dec_tok, const float* __restrict__ mask_token,
                            const float* __restrict__ dec_pos, const int* __restrict__ mi,
                            ushort_t* __restrict__ Xd, float* __restrict__ out0, int base) {
    int s = blockIdx.x;
    int g = base + s;
    int t = threadIdx.x;
    for (int idx = t; idx < N_SEQ * DD; idx += 256) {
        int i = idx / DD, d = idx % DD;
        float v;
        if (i < NM) {
            int m = mi[g * NM + i];
            v = mask_token[d] + dec_pos[(size_t)m * DD + d];
        } else {
            v = bf2f(dec_tok[((size_t)s * NU + (i - NM)) * DD + d]);
        }
        Xd[((size_t)s * N_SEQ + i) * DD + d] = f2bf(v);
        out0[((size_t)g * N_SEQ + i) * DD + d] = v;
    }
}

// ---------------- prediction head + loss ----------------
__global__ void k_pred(const ushort_t* __restrict__ Xd, const int* __restrict__ mi,
                       const float* __restrict__ pW, const float* __restrict__ pb,
                       const float* __restrict__ mn, float* __restrict__ out_pred,
                       float* __restrict__ loss, int base, int Bc) {
    int tid = blockIdx.x * 256 + threadIdx.x;
    int total = Bc * NM * NDIM;
    float part = 0.f;
    if (tid < total) {
        int c = tid % NDIM;
        int r = tid / NDIM;
        int i = r % NM;
        int s = r / NM;
        int g = base + s;
        int m = mi[g * NM + i];
        const ushort_t* row = Xd + ((size_t)s * N_SEQ + m) * DD;
        float acc = pb[c];
        for (int k = 0; k < DD; ++k) acc += bf2f(row[k]) * pW[k * NDIM + c];
        out_pred[((size_t)g * NM + i) * NDIM + c] = acc;
        float d = acc - mn[((size_t)g * NM + i) * NDIM + c];
        part = d * d;
    }
    __shared__ float red[256];
    red[threadIdx.x] = part;
    __syncthreads();
    for (int o = 128; o > 0; o >>= 1) {
        if (threadIdx.x < o) red[threadIdx.x] += red[threadIdx.x + o];
        __syncthreads();
    }
    if (threadIdx.x == 0) atomicAdd(loss, red[0]);
}

// ---------------- host ----------------
extern "C" void kernel_launch(void* const* d_in, const int* in_sizes, int n_in,
                              void* d_out, int out_size, void* d_ws, size_t ws_size,
                              hipStream_t stream) {
    const float* x       = (const float*)d_in[0];
    const float* a       = (const float*)d_in[1];
    const int*   mi      = (const int*)d_in[2];
    const int*   ui      = (const int*)d_in[3];
    const float* W_emb   = (const float*)d_in[4];
    const float* b_emb   = (const float*)d_in[5];
    const float* pos_emb = (const float*)d_in[6];
    const float* e_ln1_s = (const float*)d_in[7];
    const float* e_ln1_b = (const float*)d_in[8];
    const float* e_Wqkv  = (const float*)d_in[9];
    const float* e_Wo    = (const float*)d_in[10];
    const float* e_bo    = (const float*)d_in[11];
    const float* e_ln2_s = (const float*)d_in[12];
    const float* e_ln2_b = (const float*)d_in[13];
    const float* e_W1    = (const float*)d_in[14];
    const float* e_b1    = (const float*)d_in[15];
    const float* e_W2    = (const float*)d_in[16];
    const float* e_b2    = (const float*)d_in[17];
    const float* e2d_W   = (const float*)d_in[18];
    const float* e2d_b   = (const float*)d_in[19];
    const float* mask_tok= (const float*)d_in[20];
    const float* dec_pos = (const float*)d_in[21];
    const float* d_ln1_s = (const float*)d_in[22];
    const float* d_ln1_b = (const float*)d_in[23];
    const float* d_Wqkv  = (const float*)d_in[24];
    const float* d_Wo    = (const float*)d_in[25];
    const float* d_bo    = (const float*)d_in[26];
    const float* d_ln2_s = (const float*)d_in[27];
    const float* d_ln2_b = (const float*)d_in[28];
    const float* d_W1    = (const float*)d_in[29];
    const float* d_b1    = (const float*)d_in[30];
    const float* d_W2    = (const float*)d_in[31];
    const float* d_b2    = (const float*)d_in[32];
    const float* pred_W  = (const float*)d_in[33];
    const float* pred_b  = (const float*)d_in[34];

    float* out0 = (float*)d_out;
    float* out1 = out0 + (size_t)B_TOT * N_SEQ * DD;
    float* out2 = out1 + (size_t)B_TOT * NM * NDIM;
    float* out3 = out2 + (size_t)B_TOT * NM;
    float* out4 = out3 + (size_t)B_TOT * NM * NDIM;

    // ---- workspace layout ----
    char* wp = (char*)d_ws;
    size_t off = 0;
    auto alloc = [&](size_t bytes) {
        size_t o = off;
        off = (off + bytes + 255) & ~(size_t)255;
        return (void*)(wp + o);
    };
    float* loss_acc = (float*)alloc(64 * 4);
    ushort_t* wt_eqkv = (ushort_t*)alloc((size_t)2 * 1536 * 512 * 2);
    ushort_t* wt_ewo  = (ushort_t*)alloc((size_t)2 * 512 * 512 * 2);
    ushort_t* wt_ew1  = (ushort_t*)alloc((size_t)2 * 2048 * 512 * 2);
    ushort_t* wt_ew2  = (ushort_t*)alloc((size_t)2 * 512 * 2048 * 2);
    ushort_t* wt_dqkv = (ushort_t*)alloc((size_t)1536 * 256 * 2);
    ushort_t* wt_dwo  = (ushort_t*)alloc((size_t)256 * 512 * 2);
    ushort_t* wt_dw1  = (ushort_t*)alloc((size_t)1024 * 256 * 2);
    ushort_t* wt_dw2  = (ushort_t*)alloc((size_t)256 * 1024 * 2);
    ushort_t* wt_e2d  = (ushort_t*)alloc((size_t)256 * 512 * 2);
    size_t fixed_bytes = off;

    // per-seq bytes: bf16 (X 7168 + H 7168 + QKV 43008) + f32 ua 196.
    // Dbuf (3584 u16/seq) ALIASES the head of QKVbuf: QKV is dead when e2d writes
    // Dbuf, and dqkv overwrites it only after build_dec consumed Dbuf.
    const size_t per_seq = 2 * (7168 + 7168 + 43008) + 4 * 196;
    int Bc = B_TOT;
    while (Bc > 64 && fixed_bytes + (size_t)Bc * per_seq + 8192 > ws_size) Bc >>= 1;

    ushort_t* Xbuf   = (ushort_t*)alloc((size_t)Bc * 7168 * 2);
    float*    uabuf  = (float*)alloc((size_t)Bc * 196 * 4);
    ushort_t* Hbuf   = (ushort_t*)alloc((size_t)Bc * 7168 * 2);
    ushort_t* QKVbuf = (ushort_t*)alloc((size_t)Bc * 43008 * 2);
    ushort_t* Dbuf   = QKVbuf;  // alias (see above)

    k_zero<<<1, 64, 0, stream>>>(loss_acc);

    // ---- weight conversion (once per launch) ----
    for (int l = 0; l < 2; ++l) {
        k_wconv<<<dim3(1536 / 32, 512 / 32), 256, 0, stream>>>(e_Wqkv + (size_t)l * 512 * 1536, wt_eqkv + (size_t)l * 1536 * 512, 512, 1536);
        k_wconv<<<dim3(512 / 32, 512 / 32), 256, 0, stream>>>(e_Wo + (size_t)l * 512 * 512, wt_ewo + (size_t)l * 512 * 512, 512, 512);
        k_wconv<<<dim3(2048 / 32, 512 / 32), 256, 0, stream>>>(e_W1 + (size_t)l * 512 * 2048, wt_ew1 + (size_t)l * 2048 * 512, 512, 2048);
        k_wconv<<<dim3(512 / 32, 2048 / 32), 256, 0, stream>>>(e_W2 + (size_t)l * 2048 * 512, wt_ew2 + (size_t)l * 512 * 2048, 2048, 512);
    }
    k_wconv<<<dim3(1536 / 32, 256 / 32), 256, 0, stream>>>(d_Wqkv, wt_dqkv, 256, 1536);
    k_wconv<<<dim3(256 / 32, 512 / 32), 256, 0, stream>>>(d_Wo, wt_dwo, 512, 256);
    k_wconv<<<dim3(1024 / 32, 256 / 32), 256, 0, stream>>>(d_W1, wt_dw1, 256, 1024);
    k_wconv<<<dim3(256 / 32, 1024 / 32), 256, 0, stream>>>(d_W2, wt_dw2, 1024, 256);
    k_wconv<<<dim3(256 / 32, 512 / 32), 256, 0, stream>>>(e2d_W, wt_e2d, 512, 256);

    const int nchunk = B_TOT / Bc;
    for (int c = 0; c < nchunk; ++c) {
        int base = c * Bc;
        int M = Bc * NU;
        int Md = Bc * N_SEQ;

        k_embed<<<Bc, 256, 0, stream>>>(x, a, mi, ui, W_emb, b_emb, pos_emb,
                                        Xbuf, uabuf, out1, out2, base);
        // ---- encoder ----
        for (int l = 0; l < 2; ++l) {
            k_ln<ED><<<M / 4, 256, 0, stream>>>(Xbuf, Hbuf, e_ln1_s + l * ED, e_ln1_b + l * ED, M);
            k_gemm_mfma<0><<<dim3(1536 / 128, M / 128), 256, 0, stream>>>(
                Hbuf, wt_eqkv + (size_t)l * 1536 * 512, nullptr, nullptr, QKVbuf, M, 1536, ED, ED);
            k_attn_mfma<NU><<<dim3(Bc, 2), 256, 0, stream>>>(QKVbuf, uabuf);
            k_gemm_mfma<0><<<dim3(ED / 128, M / 128), 256, 0, stream>>>(
                QKVbuf, wt_ewo + (size_t)l * 512 * 512, e_bo + l * ED, Xbuf, Xbuf, M, ED, 512, 1536);
            k_ln<ED><<<M / 4, 256, 0, stream>>>(Xbuf, Hbuf, e_ln2_s + l * ED, e_ln2_b + l * ED, M);
            k_gemm_mfma<1><<<dim3(EMLP / 128, M / 128), 256, 0, stream>>>(
                Hbuf, wt_ew1 + (size_t)l * 2048 * 512, e_b1 + l * EMLP, nullptr, QKVbuf, M, EMLP, ED, ED);
            k_gemm_mfma<0><<<dim3(ED / 128, M / 128), 256, 0, stream>>>(
                QKVbuf, wt_ew2 + (size_t)l * 512 * 2048, e_b2 + l * ED, Xbuf, Xbuf, M, ED, EMLP, EMLP);
        }
        // ---- encoder -> decoder ----
        k_gemm_mfma<0><<<dim3(DD / 128, M / 128), 256, 0, stream>>>(
            Xbuf, wt_e2d, e2d_b, nullptr, Dbuf, M, DD, ED, ED);
        k_build_dec<<<Bc, 256, 0, stream>>>(Dbuf, mask_tok, dec_pos, mi, Xbuf, out0, base);
        // ---- decoder ----
        k_ln<DD><<<Md / 4, 256, 0, stream>>>(Xbuf, Hbuf, d_ln1_s, d_ln1_b, Md);
        k_gemm_mfma<0><<<dim3(1536 / 128, Md / 128), 256, 0, stream>>>(
            Hbuf, wt_dqkv, nullptr, nullptr, QKVbuf, Md, 1536, DD, DD);
        k_attn_mfma<N_SEQ><<<dim3(Bc, 2), 256, 0, stream>>>(QKVbuf, a + (size_t)base * N_SEQ * N_SEQ);
        k_gemm_mfma<0><<<dim3(DD / 128, Md / 128), 256, 0, stream>>>(
            QKVbuf, wt_dwo, d_bo, Xbuf, Xbuf, Md, DD, 512, 1536);
        k_ln<DD><<<Md / 4, 256, 0, stream>>>(Xbuf, Hbuf, d_ln2_s, d_ln2_b, Md);
        k_gemm_mfma<1><<<dim3(DMLP / 128, Md / 128), 256, 0, stream>>>(
            Hbuf, wt_dw1, d_b1, nullptr, QKVbuf, Md, DMLP, DD, DD);
        k_gemm_mfma<0><<<dim3(DD / 128, Md / 128), 256, 0, stream>>>(
            QKVbuf, wt_dw2, d_b2, Xbuf, Xbuf, Md, DD, DMLP, DMLP);
        // ---- prediction + loss ----
        int tot = Bc * NM * NDIM;
        k_pred<<<(tot + 255) / 256, 256, 0, stream>>>(
            Xbuf, mi, pred_W, pred_b, out1, out3, loss_acc, base, Bc);
    }
    k_final<<<1, 1, 0, stream>>>(loss_acc, out4);
}